// Round 11
// baseline (1402.690 us; speedup 1.0000x reference)
//
#include <hip/hip_runtime.h>
#include <stdint.h>

#define T_TOKENS 16384
#define HID 1024
#define INTERM 2048
#define NEXP 8

typedef __bf16 bf16x8 __attribute__((ext_vector_type(8)));
typedef float f32x4 __attribute__((ext_vector_type(4)));

// ---------- helpers ----------
__device__ __forceinline__ unsigned short f2bf(float f) {
  union { float f; uint32_t u; } v; v.f = f;
  uint32_t u = v.u + 0x7fffu + ((v.u >> 16) & 1u);
  return (unsigned short)(u >> 16);
}

__device__ __forceinline__ float bf2f(unsigned short u) {
  union { uint32_t u; float f; } v; v.u = ((uint32_t)u) << 16;
  return v.f;
}

__device__ __forceinline__ void async16(const void* g, void* l) {
  auto gp = (const __attribute__((address_space(1))) uint32_t*)(uintptr_t)g;
  auto lp = (__attribute__((address_space(3))) uint32_t*)(uintptr_t)l;
  __builtin_amdgcn_global_load_lds(gp, lp, 16, 0, 0);
}

// tanh-form gelu via fast exp: max abs err ~3e-4 vs exact erf-gelu
__device__ __forceinline__ float gelu_fast(float v) {
  float s = 1.5957691216f * v + 0.0713548163f * v * v * v;
  return v / (1.f + __expf(-s));
}

// ---------- fp32 -> bf16 cast (weights) ----------
__global__ void cast_bf16_kernel(const float* __restrict__ in,
                                 unsigned short* __restrict__ out, int n) {
  int stride = gridDim.x * blockDim.x;
  for (int i = blockIdx.x * blockDim.x + threadIdx.x; i < (n >> 2); i += stride) {
    float4 v = reinterpret_cast<const float4*>(in)[i];
    ushort4 o;
    o.x = f2bf(v.x); o.y = f2bf(v.y); o.z = f2bf(v.z); o.w = f2bf(v.w);
    reinterpret_cast<ushort4*>(out)[i] = o;
  }
}

// ---------- routing: wave/token dot, LDS histogram (NO global atomics) ----------
__global__ __launch_bounds__(256, 4) void routing_kernel(
    const float* __restrict__ x, const float* __restrict__ gw,
    float* __restrict__ logits, unsigned short* __restrict__ xb,
    int* __restrict__ bh, int* __restrict__ tok_e01, float2* __restrict__ tok_w) {
  __shared__ float4 gws[2048];  // 8 experts x 1024 floats = 32 KB
  __shared__ int lh[16];
  const int tid = threadIdx.x;
  if (tid < 16) lh[tid] = 0;
  for (int i = tid; i < 2048; i += 256)
    gws[i] = reinterpret_cast<const float4*>(gw)[i];
  __syncthreads();

  const int lane = tid & 63;
  const int wave = tid >> 6;
  const int tbase = blockIdx.x * 16 + wave * 4;
#pragma unroll 2
  for (int j = 0; j < 4; ++j) {
    int t = tbase + j;
    const float4* xr = reinterpret_cast<const float4*>(x + (size_t)t * HID);
    float4 xv[4];
#pragma unroll
    for (int q = 0; q < 4; ++q) xv[q] = xr[q * 64 + lane];
    ushort4* xbr = reinterpret_cast<ushort4*>(xb + (size_t)t * HID);
#pragma unroll
    for (int q = 0; q < 4; ++q) {
      ushort4 o;
      o.x = f2bf(xv[q].x); o.y = f2bf(xv[q].y);
      o.z = f2bf(xv[q].z); o.w = f2bf(xv[q].w);
      xbr[q * 64 + lane] = o;
    }
    float acc[NEXP];
#pragma unroll
    for (int e = 0; e < NEXP; ++e) {
      float a = 0.f;
#pragma unroll
      for (int q = 0; q < 4; ++q) {
        float4 g = gws[e * 256 + q * 64 + lane];
        a += xv[q].x * g.x + xv[q].y * g.y + xv[q].z * g.z + xv[q].w * g.w;
      }
      acc[e] = a;
    }
#pragma unroll
    for (int e = 0; e < NEXP; ++e)
#pragma unroll
      for (int off = 32; off > 0; off >>= 1)
        acc[e] += __shfl_xor(acc[e], off, 64);
    if (lane == 0) {
      int i0 = 0; float m0 = acc[0];
#pragma unroll
      for (int e = 1; e < NEXP; ++e) if (acc[e] > m0) { m0 = acc[e]; i0 = e; }
      int i1 = -1; float m1 = -3.4e38f;
#pragma unroll
      for (int e = 0; e < NEXP; ++e) if (e != i0 && acc[e] > m1) { m1 = acc[e]; i1 = e; }
      float w0 = 1.f / (1.f + expf(m1 - m0));
      float w1 = 1.f - w0;
      atomicAdd(&lh[i0], 1);
      atomicAdd(&lh[8 + i1], 1);
      tok_e01[t] = i0 | (i1 << 16);
      tok_w[t] = make_float2(w0, w1);
      float4* lg = reinterpret_cast<float4*>(logits + (size_t)t * NEXP);
      lg[0] = make_float4(acc[0], acc[1], acc[2], acc[3]);
      lg[1] = make_float4(acc[4], acc[5], acc[6], acc[7]);
    }
  }
  __syncthreads();
  if (tid < 16) bh[blockIdx.x * 16 + tid] = lh[tid];
}

// ---------- parallel schedule: column prefix scans + 128-row tile emission ----------
// Single tile list (expert-grouped rows) used by BOTH GEMMs.
__global__ __launch_bounds__(1024) void sched_kernel(
    const int* __restrict__ bh, int* __restrict__ bhp, int* __restrict__ colbase,
    int4* __restrict__ sched1, int* __restrict__ nsched) {
  const int tid = threadIdx.x;
  const int w = tid >> 6;
  const int lane = tid & 63;
  __shared__ int ct[16];
  __shared__ int offs[8];
  __shared__ int t1o[8];

  int carry = 0;
  for (int ch = 0; ch < 16; ++ch) {
    int b = ch * 64 + lane;
    int v = bh[b * 16 + w];
    int incl = v;
#pragma unroll
    for (int d = 1; d < 64; d <<= 1) {
      int tt = __shfl_up(incl, d, 64);
      if (lane >= d) incl += tt;
    }
    bhp[b * 16 + w] = incl - v + carry;
    carry += __shfl(incl, 63, 64);
  }
  if (lane == 0) ct[w] = carry;
  __syncthreads();
  if (tid == 0) {
    int o = 0, s1 = 0;
    for (int e = 0; e < NEXP; ++e) {
      offs[e] = o;
      int n = ct[e] + ct[8 + e];
      o += n;
      t1o[e] = s1;
      s1 += (n + 127) >> 7;
    }
    nsched[0] = s1;
  }
  __syncthreads();
  if (tid < 16) colbase[tid] = offs[tid & 7] + ((tid & 8) ? ct[tid & 7] : 0);
  if (tid < 8) {
    int e = tid;
    int n = ct[e] + ct[8 + e], o = offs[e];
    for (int i = 0, t0 = 0; t0 < n; t0 += 128, ++i) {
      int hi = t0 + 128 < n ? t0 + 128 : n;
      sched1[t1o[e] + i] = make_int4(o + t0, o + hi, e, 0);
    }
  }
}

// ---------- scatter: per-block LDS ranks + precomputed bases ----------
__global__ __launch_bounds__(64) void scatter_kernel(
    const int* __restrict__ tok_e01, const float2* __restrict__ tok_w,
    const int* __restrict__ bhp, const int* __restrict__ colbase,
    int* __restrict__ row_token, float* __restrict__ row_weight,
    int2* __restrict__ tok_pos) {
  __shared__ int lh[16];
  const int tid = threadIdx.x;
  if (tid < 16) lh[tid] = 0;
  __syncthreads();
  if (tid < 16) {
    int t = blockIdx.x * 16 + tid;
    int p = tok_e01[t];
    int e0 = p & 0xffff, e1 = p >> 16;
    float2 w = tok_w[t];
    int r0 = atomicAdd(&lh[e0], 1);
    int pos0 = colbase[e0] + bhp[blockIdx.x * 16 + e0] + r0;
    row_token[pos0] = t; row_weight[pos0] = w.x;
    int r1 = atomicAdd(&lh[8 + e1], 1);
    int pos1 = colbase[8 + e1] + bhp[blockIdx.x * 16 + 8 + e1] + r1;
    row_token[pos1] = t; row_weight[pos1] = w.y;
    tok_pos[t] = make_int2(pos0, pos1);
  }
}

// ---------- grouped GEMM 128x128xBK64, 4 waves, m97-structure ----------
// 2D grid, col fastest (R9 layout — DO NOT remap): round-robin XCD dispatch
// pins XCD k to col-blocks {k, k+8} -> B partitioned across XCDs (512 KB/XCD,
// L2-resident, fetched once chip-wide); A broadcasts via 256 MiB L3. R10's
// sid-chunk remap put 4 MB B panel + A tiles in one 4 MiB L2 -> B re-fetched
// per sid (940 MB FETCH, 2.3x slower). Occupancy 5 blocks/CU (160 KB LDS).
// T2 both-sides swizzle (bank conflicts 0, verified R5-R10).
// MODE 0: A gathered via row_token, epilogue gelu(.+b1) -> h (bf16)
// MODE 1: A = h rows (contiguous), epilogue y[row] = bf16(w*(acc+b2))
template <int MODE, int KDIM, int NDIM>
__global__ __launch_bounds__(256, 5) void gemm128_kernel(
    const unsigned short* __restrict__ A, const unsigned short* __restrict__ Bw,
    const float* __restrict__ bias, unsigned short* __restrict__ hOut,
    const int* __restrict__ row_token, const float* __restrict__ row_weight,
    const int4* __restrict__ sched, const int* __restrict__ nsched_p) {
  const int sid = blockIdx.y;  // blockIdx.x = col (fastest) -> XCD = col%8
  if (sid >= nsched_p[0]) return;
  int4 s = sched[sid];
  const int row_start = s.x, row_limit = s.y, e = s.z;
  const int colBase = blockIdx.x * 128;

  __shared__ __attribute__((aligned(16))) unsigned short As[128 * 64];  // 16 KB
  __shared__ __attribute__((aligned(16))) unsigned short Bs[128 * 64];  // 16 KB

  const int tid = threadIdx.x;
  const int wave = tid >> 6;
  const int lane = tid & 63;
  const int wr = wave >> 1;  // 0..1 (M half)
  const int wc = wave & 1;   // 0..1 (N half)

  // staging: thread covers (row = i*32 + tid>>3, phys chunk tid&7); T2 write
  // side fetches logical chunk (tid&7)^(row&7), row&7 == (tid>>3)&7
  const int schunk = (tid & 7) ^ ((tid >> 3) & 7);
  const unsigned short* aG[4];
  const unsigned short* bG[4];
  const unsigned short* Bbase = Bw + (size_t)e * ((size_t)NDIM * KDIM);
#pragma unroll
  for (int i = 0; i < 4; ++i) {
    int r = i * 32 + (tid >> 3);
    int rg = row_start + r;
    rg = rg < row_limit ? rg : (row_limit - 1);  // clamp partial tiles
    int arow = (MODE == 0) ? row_token[rg] : rg;
    aG[i] = A + (size_t)arow * KDIM + schunk * 8;
    bG[i] = Bbase + (size_t)(colBase + r) * KDIM + schunk * 8;
  }

  f32x4 zero = {0.f, 0.f, 0.f, 0.f};
  f32x4 acc[4][4];
#pragma unroll
  for (int m = 0; m < 4; ++m)
#pragma unroll
    for (int n = 0; n < 4; ++n) acc[m][n] = zero;

  const int rl = lane & 15;
  const int ch0 = lane >> 4;
  const int swz = rl & 7;
  const int cOff0 = (ch0 ^ swz) * 16;        // ks0 swizzled chunk byte
  const int cOff1 = ((4 + ch0) ^ swz) * 16;  // ks1
  const int arB = (wr * 64 + rl) * 128;      // A frag row-base byte (+m*2048)
  const int brB = (wc * 64 + rl) * 128;      // B frag row-base byte (+n*2048)

  for (int kt = 0; kt < KDIM / 64; ++kt) {
    if (kt) __syncthreads();  // all waves done reading previous tile
    const size_t koff = (size_t)kt * 64;  // elements (128 B)
#pragma unroll
    for (int i = 0; i < 4; ++i) {
      async16(aG[i] + koff, (char*)As + (i * 4 + wave) * 1024);
      async16(bG[i] + koff, (char*)Bs + (i * 4 + wave) * 1024);
    }
    __syncthreads();  // compiler drains vmcnt(0) before s_barrier: tile ready
#pragma unroll
    for (int ks = 0; ks < 2; ++ks) {
      const int co = ks ? cOff1 : cOff0;
      bf16x8 af[4], bfr[4];
#pragma unroll
      for (int m = 0; m < 4; ++m)
        af[m] = *reinterpret_cast<const bf16x8*>((const char*)As + arB + m * 2048 + co);
#pragma unroll
      for (int n = 0; n < 4; ++n)
        bfr[n] = *reinterpret_cast<const bf16x8*>((const char*)Bs + brB + n * 2048 + co);
#pragma unroll
      for (int m = 0; m < 4; ++m)
#pragma unroll
        for (int n = 0; n < 4; ++n)
          acc[m][n] = __builtin_amdgcn_mfma_f32_16x16x32_bf16(af[m], bfr[n], acc[m][n], 0, 0, 0);
    }
  }

  // epilogue: C/D map col=lane&15, row=(lane>>4)*4+j
  const int cCol = lane & 15;
  const int cRowB = (lane >> 4) * 4;

  if (MODE == 0) {
#pragma unroll
    for (int n = 0; n < 4; ++n) {
      int col = colBase + wc * 64 + n * 16 + cCol;
      float bb = bias[e * NDIM + col];
#pragma unroll
      for (int m = 0; m < 4; ++m) {
#pragma unroll
        for (int j = 0; j < 4; ++j) {
          int r = row_start + wr * 64 + m * 16 + cRowB + j;
          if (r < row_limit) {
            float v = gelu_fast(acc[m][n][j] + bb);
            hOut[(size_t)r * NDIM + col] = f2bf(v);
          }
        }
      }
    }
  } else {
#pragma unroll
    for (int m = 0; m < 4; ++m) {
#pragma unroll
      for (int j = 0; j < 4; ++j) {
        int rr = row_start + wr * 64 + m * 16 + cRowB + j;
        if (rr < row_limit) {
          float wgt = row_weight[rr];
          unsigned short* yrow = hOut + (size_t)rr * NDIM;
#pragma unroll
          for (int n = 0; n < 4; ++n) {
            int col = colBase + wc * 64 + n * 16 + cCol;
            yrow[col] = f2bf(wgt * (acc[m][n][j] + bias[e * NDIM + col]));
          }
        }
      }
    }
  }
}

// ---------- combine: out[t] = y[pos0] + y[pos1] (wave per token) ----------
__global__ __launch_bounds__(256) void combine_kernel(
    const unsigned short* __restrict__ y, const int2* __restrict__ tok_pos,
    float* __restrict__ out) {
  const int t = blockIdx.x * 4 + (threadIdx.x >> 6);
  const int lane = threadIdx.x & 63;
  int2 p = tok_pos[t];
  const ushort4* y0 = reinterpret_cast<const ushort4*>(y + (size_t)p.x * HID);
  const ushort4* y1 = reinterpret_cast<const ushort4*>(y + (size_t)p.y * HID);
  float4* o = reinterpret_cast<float4*>(out + (size_t)t * HID);
#pragma unroll
  for (int q = 0; q < 4; ++q) {
    ushort4 a = y0[q * 64 + lane];
    ushort4 b = y1[q * 64 + lane];
    float4 r;
    r.x = bf2f(a.x) + bf2f(b.x);
    r.y = bf2f(a.y) + bf2f(b.y);
    r.z = bf2f(a.z) + bf2f(b.z);
    r.w = bf2f(a.w) + bf2f(b.w);
    o[q * 64 + lane] = r;
  }
}

// ---------- launch ----------
extern "C" void kernel_launch(void* const* d_in, const int* in_sizes, int n_in,
                              void* d_out, int out_size, void* d_ws, size_t ws_size,
                              hipStream_t stream) {
  const float* x  = (const float*)d_in[0];
  const float* gw = (const float*)d_in[1];
  const float* w1 = (const float*)d_in[2];
  const float* b1 = (const float*)d_in[3];
  const float* w2 = (const float*)d_in[4];
  const float* b2 = (const float*)d_in[5];
  float* out = (float*)d_out;
  float* logits = out + (size_t)T_TOKENS * HID;

  char* ws = (char*)d_ws;
  int* nsched = (int*)ws;
  int* colbase = (int*)(ws + 64);
  int4* sched1  = (int4*)(ws + 512);               // <=264 entries
  int* tok_e01 = (int*)(ws + 16384);                              // 64 KB
  float2* tok_w = (float2*)(ws + 16384 + 65536);                  // 128 KB
  int* row_token = (int*)(ws + 16384 + 65536 + 131072);           // 128 KB
  float* row_weight = (float*)(ws + 16384 + 65536 + 2 * 131072);  // 128 KB
  int* bh  = (int*)(ws + 16384 + 65536 + 3 * 131072);             // 64 KB
  int* bhp = bh + 16384;                                          // 64 KB
  int2* tok_pos = (int2*)(ws + 16384 + 65536 + 3 * 131072 + 2 * 65536);  // 128 KB
  const size_t BIG = 1u << 20;
  unsigned short* xb  = (unsigned short*)(ws + BIG);  // 32 MiB
  unsigned short* w1b = xb  + (size_t)16777216;       // 32 MiB
  unsigned short* w2b = w1b + (size_t)16777216;       // 32 MiB
  unsigned short* h   = w2b + (size_t)16777216;       // 128 MiB
  // y (32768 x 1024 bf16 = 64 MiB) aliases [xb, w1b]: both dead after GEMM1
  unsigned short* y = xb;
  const size_t REQUIRED = BIG + 3ull * 33554432ull + 134217728ull;
  if (ws_size < REQUIRED) return;

  cast_bf16_kernel<<<2048, 256, 0, stream>>>(w1, w1b, 16777216);
  cast_bf16_kernel<<<2048, 256, 0, stream>>>(w2, w2b, 16777216);
  routing_kernel<<<1024, 256, 0, stream>>>(x, gw, logits, xb, bh, tok_e01, tok_w);
  sched_kernel<<<1, 1024, 0, stream>>>(bh, bhp, colbase, sched1, nsched);
  scatter_kernel<<<1024, 64, 0, stream>>>(tok_e01, tok_w, bhp, colbase,
                                          row_token, row_weight, tok_pos);
  // GEMM1: h = gelu(x @ w1^T + b1); <=263 row-tiles x 16 col-blocks
  gemm128_kernel<0, 1024, 2048><<<dim3(16, 264), 256, 0, stream>>>(
      xb, w1b, b1, h, row_token, nullptr, sched1, nsched);
  // GEMM2 single pass: y[row] = bf16(w*(h @ w2^T + b2)); 8 col-blocks
  gemm128_kernel<1, 2048, 1024><<<dim3(8, 264), 256, 0, stream>>>(
      h, w2b, b2, y, row_token, row_weight, sched1, nsched);
  // combine: out[t] = y[pos0(t)] + y[pos1(t)]
  combine_kernel<<<4096, 256, 0, stream>>>(y, tok_pos, out);
}

// Round 12
// 599.523 us; speedup vs baseline: 2.3397x; 2.3397x over previous
//
#include <hip/hip_runtime.h>
#include <stdint.h>

#define T_TOKENS 16384
#define HID 1024
#define INTERM 2048
#define NEXP 8

typedef __bf16 bf16x8 __attribute__((ext_vector_type(8)));
typedef float f32x4 __attribute__((ext_vector_type(4)));

// ---------- helpers ----------
__device__ __forceinline__ unsigned short f2bf(float f) {
  union { float f; uint32_t u; } v; v.f = f;
  uint32_t u = v.u + 0x7fffu + ((v.u >> 16) & 1u);
  return (unsigned short)(u >> 16);
}

__device__ __forceinline__ float bf2f(unsigned short u) {
  union { uint32_t u; float f; } v; v.u = ((uint32_t)u) << 16;
  return v.f;
}

__device__ __forceinline__ void async16(const void* g, void* l) {
  auto gp = (const __attribute__((address_space(1))) uint32_t*)(uintptr_t)g;
  auto lp = (__attribute__((address_space(3))) uint32_t*)(uintptr_t)l;
  __builtin_amdgcn_global_load_lds(gp, lp, 16, 0, 0);
}

// tanh-form gelu via fast exp: max abs err ~3e-4 vs exact erf-gelu
__device__ __forceinline__ float gelu_fast(float v) {
  float s = 1.5957691216f * v + 0.0713548163f * v * v * v;
  return v / (1.f + __expf(-s));
}

// ---------- fp32 -> bf16 cast (weights) ----------
__global__ void cast_bf16_kernel(const float* __restrict__ in,
                                 unsigned short* __restrict__ out, int n) {
  int stride = gridDim.x * blockDim.x;
  for (int i = blockIdx.x * blockDim.x + threadIdx.x; i < (n >> 2); i += stride) {
    float4 v = reinterpret_cast<const float4*>(in)[i];
    ushort4 o;
    o.x = f2bf(v.x); o.y = f2bf(v.y); o.z = f2bf(v.z); o.w = f2bf(v.w);
    reinterpret_cast<ushort4*>(out)[i] = o;
  }
}

// ---------- routing: wave/token dot, LDS histogram (NO global atomics) ----------
__global__ __launch_bounds__(256, 4) void routing_kernel(
    const float* __restrict__ x, const float* __restrict__ gw,
    float* __restrict__ logits, unsigned short* __restrict__ xb,
    int* __restrict__ bh, int* __restrict__ tok_e01, float2* __restrict__ tok_w) {
  __shared__ float4 gws[2048];  // 8 experts x 1024 floats = 32 KB
  __shared__ int lh[16];
  const int tid = threadIdx.x;
  if (tid < 16) lh[tid] = 0;
  for (int i = tid; i < 2048; i += 256)
    gws[i] = reinterpret_cast<const float4*>(gw)[i];
  __syncthreads();

  const int lane = tid & 63;
  const int wave = tid >> 6;
  const int tbase = blockIdx.x * 16 + wave * 4;
#pragma unroll 2
  for (int j = 0; j < 4; ++j) {
    int t = tbase + j;
    const float4* xr = reinterpret_cast<const float4*>(x + (size_t)t * HID);
    float4 xv[4];
#pragma unroll
    for (int q = 0; q < 4; ++q) xv[q] = xr[q * 64 + lane];
    ushort4* xbr = reinterpret_cast<ushort4*>(xb + (size_t)t * HID);
#pragma unroll
    for (int q = 0; q < 4; ++q) {
      ushort4 o;
      o.x = f2bf(xv[q].x); o.y = f2bf(xv[q].y);
      o.z = f2bf(xv[q].z); o.w = f2bf(xv[q].w);
      xbr[q * 64 + lane] = o;
    }
    float acc[NEXP];
#pragma unroll
    for (int e = 0; e < NEXP; ++e) {
      float a = 0.f;
#pragma unroll
      for (int q = 0; q < 4; ++q) {
        float4 g = gws[e * 256 + q * 64 + lane];
        a += xv[q].x * g.x + xv[q].y * g.y + xv[q].z * g.z + xv[q].w * g.w;
      }
      acc[e] = a;
    }
#pragma unroll
    for (int e = 0; e < NEXP; ++e)
#pragma unroll
      for (int off = 32; off > 0; off >>= 1)
        acc[e] += __shfl_xor(acc[e], off, 64);
    if (lane == 0) {
      int i0 = 0; float m0 = acc[0];
#pragma unroll
      for (int e = 1; e < NEXP; ++e) if (acc[e] > m0) { m0 = acc[e]; i0 = e; }
      int i1 = -1; float m1 = -3.4e38f;
#pragma unroll
      for (int e = 0; e < NEXP; ++e) if (e != i0 && acc[e] > m1) { m1 = acc[e]; i1 = e; }
      float w0 = 1.f / (1.f + expf(m1 - m0));
      float w1 = 1.f - w0;
      atomicAdd(&lh[i0], 1);
      atomicAdd(&lh[8 + i1], 1);
      tok_e01[t] = i0 | (i1 << 16);
      tok_w[t] = make_float2(w0, w1);
      float4* lg = reinterpret_cast<float4*>(logits + (size_t)t * NEXP);
      lg[0] = make_float4(acc[0], acc[1], acc[2], acc[3]);
      lg[1] = make_float4(acc[4], acc[5], acc[6], acc[7]);
    }
  }
  __syncthreads();
  if (tid < 16) bh[blockIdx.x * 16 + tid] = lh[tid];
}

// ---------- parallel schedule: column prefix scans + 128-row tile emission ----------
// Single tile list (expert-grouped rows) used by BOTH GEMMs.
__global__ __launch_bounds__(1024) void sched_kernel(
    const int* __restrict__ bh, int* __restrict__ bhp, int* __restrict__ colbase,
    int4* __restrict__ sched1, int* __restrict__ nsched) {
  const int tid = threadIdx.x;
  const int w = tid >> 6;
  const int lane = tid & 63;
  __shared__ int ct[16];
  __shared__ int offs[8];
  __shared__ int t1o[8];

  int carry = 0;
  for (int ch = 0; ch < 16; ++ch) {
    int b = ch * 64 + lane;
    int v = bh[b * 16 + w];
    int incl = v;
#pragma unroll
    for (int d = 1; d < 64; d <<= 1) {
      int tt = __shfl_up(incl, d, 64);
      if (lane >= d) incl += tt;
    }
    bhp[b * 16 + w] = incl - v + carry;
    carry += __shfl(incl, 63, 64);
  }
  if (lane == 0) ct[w] = carry;
  __syncthreads();
  if (tid == 0) {
    int o = 0, s1 = 0;
    for (int e = 0; e < NEXP; ++e) {
      offs[e] = o;
      int n = ct[e] + ct[8 + e];
      o += n;
      t1o[e] = s1;
      s1 += (n + 127) >> 7;
    }
    nsched[0] = s1;
  }
  __syncthreads();
  if (tid < 16) colbase[tid] = offs[tid & 7] + ((tid & 8) ? ct[tid & 7] : 0);
  if (tid < 8) {
    int e = tid;
    int n = ct[e] + ct[8 + e], o = offs[e];
    for (int i = 0, t0 = 0; t0 < n; t0 += 128, ++i) {
      int hi = t0 + 128 < n ? t0 + 128 : n;
      sched1[t1o[e] + i] = make_int4(o + t0, o + hi, e, 0);
    }
  }
}

// ---------- scatter: per-block LDS ranks + precomputed bases ----------
__global__ __launch_bounds__(64) void scatter_kernel(
    const int* __restrict__ tok_e01, const float2* __restrict__ tok_w,
    const int* __restrict__ bhp, const int* __restrict__ colbase,
    int* __restrict__ row_token, float* __restrict__ row_weight,
    int2* __restrict__ tok_pos) {
  __shared__ int lh[16];
  const int tid = threadIdx.x;
  if (tid < 16) lh[tid] = 0;
  __syncthreads();
  if (tid < 16) {
    int t = blockIdx.x * 16 + tid;
    int p = tok_e01[t];
    int e0 = p & 0xffff, e1 = p >> 16;
    float2 w = tok_w[t];
    int r0 = atomicAdd(&lh[e0], 1);
    int pos0 = colbase[e0] + bhp[blockIdx.x * 16 + e0] + r0;
    row_token[pos0] = t; row_weight[pos0] = w.x;
    int r1 = atomicAdd(&lh[8 + e1], 1);
    int pos1 = colbase[8 + e1] + bhp[blockIdx.x * 16 + 8 + e1] + r1;
    row_token[pos1] = t; row_weight[pos1] = w.y;
    tok_pos[t] = make_int2(pos0, pos1);
  }
}

// ---------- grouped GEMM 128x128xBK64, 4 waves, m97-structure ----------
// 2D grid, col fastest (R9 layout): round-robin XCD dispatch pins XCD k to
// col-blocks {k, k+8} -> B partitioned across XCDs (512 KB/XCD, L2-resident);
// A broadcasts via 256 MiB L3 (FETCH ~316 MB, verified R8/R9).
// LAUNCH BOUNDS: (256) with NO min-waves clause. R10/R11's (256,5) forced
// VGPR 64->48 < live state (acc[4][4]=64 regs) -> accumulator SPILL to
// scratch: FETCH/WRITE ~1GB/950MB, MfmaUtil 8.5%, 2.4x slower. Without the
// clause the allocator takes ~64-96 VGPR (<=102 keeps 5 waves/SIMD) and the
// LDS cap alone admits 5 blocks/CU (5 x 32 KB = 160 KB).
// T2 both-sides swizzle (bank conflicts 0, verified R5-R11).
// MODE 0: A gathered via row_token, epilogue gelu(.+b1) -> h (bf16)
// MODE 1: A = h rows (contiguous), epilogue y[row] = bf16(w*(acc+b2))
template <int MODE, int KDIM, int NDIM>
__global__ __launch_bounds__(256) void gemm128_kernel(
    const unsigned short* __restrict__ A, const unsigned short* __restrict__ Bw,
    const float* __restrict__ bias, unsigned short* __restrict__ hOut,
    const int* __restrict__ row_token, const float* __restrict__ row_weight,
    const int4* __restrict__ sched, const int* __restrict__ nsched_p) {
  const int sid = blockIdx.y;  // blockIdx.x = col (fastest) -> XCD = col%8
  if (sid >= nsched_p[0]) return;
  int4 s = sched[sid];
  const int row_start = s.x, row_limit = s.y, e = s.z;
  const int colBase = blockIdx.x * 128;

  __shared__ __attribute__((aligned(16))) unsigned short As[128 * 64];  // 16 KB
  __shared__ __attribute__((aligned(16))) unsigned short Bs[128 * 64];  // 16 KB

  const int tid = threadIdx.x;
  const int wave = tid >> 6;
  const int lane = tid & 63;
  const int wr = wave >> 1;  // 0..1 (M half)
  const int wc = wave & 1;   // 0..1 (N half)

  // staging: thread covers (row = i*32 + tid>>3, phys chunk tid&7); T2 write
  // side fetches logical chunk (tid&7)^(row&7), row&7 == (tid>>3)&7
  const int schunk = (tid & 7) ^ ((tid >> 3) & 7);
  const unsigned short* aG[4];
  const unsigned short* bG[4];
  const unsigned short* Bbase = Bw + (size_t)e * ((size_t)NDIM * KDIM);
#pragma unroll
  for (int i = 0; i < 4; ++i) {
    int r = i * 32 + (tid >> 3);
    int rg = row_start + r;
    rg = rg < row_limit ? rg : (row_limit - 1);  // clamp partial tiles
    int arow = (MODE == 0) ? row_token[rg] : rg;
    aG[i] = A + (size_t)arow * KDIM + schunk * 8;
    bG[i] = Bbase + (size_t)(colBase + r) * KDIM + schunk * 8;
  }

  f32x4 zero = {0.f, 0.f, 0.f, 0.f};
  f32x4 acc[4][4];
#pragma unroll
  for (int m = 0; m < 4; ++m)
#pragma unroll
    for (int n = 0; n < 4; ++n) acc[m][n] = zero;

  const int rl = lane & 15;
  const int ch0 = lane >> 4;
  const int swz = rl & 7;
  const int cOff0 = (ch0 ^ swz) * 16;        // ks0 swizzled chunk byte
  const int cOff1 = ((4 + ch0) ^ swz) * 16;  // ks1
  const int arB = (wr * 64 + rl) * 128;      // A frag row-base byte (+m*2048)
  const int brB = (wc * 64 + rl) * 128;      // B frag row-base byte (+n*2048)

  for (int kt = 0; kt < KDIM / 64; ++kt) {
    if (kt) __syncthreads();  // all waves done reading previous tile
    const size_t koff = (size_t)kt * 64;  // elements (128 B)
#pragma unroll
    for (int i = 0; i < 4; ++i) {
      async16(aG[i] + koff, (char*)As + (i * 4 + wave) * 1024);
      async16(bG[i] + koff, (char*)Bs + (i * 4 + wave) * 1024);
    }
    __syncthreads();  // compiler drains vmcnt(0) before s_barrier: tile ready
#pragma unroll
    for (int ks = 0; ks < 2; ++ks) {
      const int co = ks ? cOff1 : cOff0;
      bf16x8 af[4], bfr[4];
#pragma unroll
      for (int m = 0; m < 4; ++m)
        af[m] = *reinterpret_cast<const bf16x8*>((const char*)As + arB + m * 2048 + co);
#pragma unroll
      for (int n = 0; n < 4; ++n)
        bfr[n] = *reinterpret_cast<const bf16x8*>((const char*)Bs + brB + n * 2048 + co);
#pragma unroll
      for (int m = 0; m < 4; ++m)
#pragma unroll
        for (int n = 0; n < 4; ++n)
          acc[m][n] = __builtin_amdgcn_mfma_f32_16x16x32_bf16(af[m], bfr[n], acc[m][n], 0, 0, 0);
    }
  }

  // epilogue: C/D map col=lane&15, row=(lane>>4)*4+j
  const int cCol = lane & 15;
  const int cRowB = (lane >> 4) * 4;

  if (MODE == 0) {
#pragma unroll
    for (int n = 0; n < 4; ++n) {
      int col = colBase + wc * 64 + n * 16 + cCol;
      float bb = bias[e * NDIM + col];
#pragma unroll
      for (int m = 0; m < 4; ++m) {
#pragma unroll
        for (int j = 0; j < 4; ++j) {
          int r = row_start + wr * 64 + m * 16 + cRowB + j;
          if (r < row_limit) {
            float v = gelu_fast(acc[m][n][j] + bb);
            hOut[(size_t)r * NDIM + col] = f2bf(v);
          }
        }
      }
    }
  } else {
#pragma unroll
    for (int m = 0; m < 4; ++m) {
#pragma unroll
      for (int j = 0; j < 4; ++j) {
        int rr = row_start + wr * 64 + m * 16 + cRowB + j;
        if (rr < row_limit) {
          float wgt = row_weight[rr];
          unsigned short* yrow = hOut + (size_t)rr * NDIM;
#pragma unroll
          for (int n = 0; n < 4; ++n) {
            int col = colBase + wc * 64 + n * 16 + cCol;
            yrow[col] = f2bf(wgt * (acc[m][n][j] + bias[e * NDIM + col]));
          }
        }
      }
    }
  }
}

// ---------- combine: out[t] = y[pos0] + y[pos1] (wave per token) ----------
__global__ __launch_bounds__(256) void combine_kernel(
    const unsigned short* __restrict__ y, const int2* __restrict__ tok_pos,
    float* __restrict__ out) {
  const int t = blockIdx.x * 4 + (threadIdx.x >> 6);
  const int lane = threadIdx.x & 63;
  int2 p = tok_pos[t];
  const ushort4* y0 = reinterpret_cast<const ushort4*>(y + (size_t)p.x * HID);
  const ushort4* y1 = reinterpret_cast<const ushort4*>(y + (size_t)p.y * HID);
  float4* o = reinterpret_cast<float4*>(out + (size_t)t * HID);
#pragma unroll
  for (int q = 0; q < 4; ++q) {
    ushort4 a = y0[q * 64 + lane];
    ushort4 b = y1[q * 64 + lane];
    float4 r;
    r.x = bf2f(a.x) + bf2f(b.x);
    r.y = bf2f(a.y) + bf2f(b.y);
    r.z = bf2f(a.z) + bf2f(b.z);
    r.w = bf2f(a.w) + bf2f(b.w);
    o[q * 64 + lane] = r;
  }
}

// ---------- launch ----------
extern "C" void kernel_launch(void* const* d_in, const int* in_sizes, int n_in,
                              void* d_out, int out_size, void* d_ws, size_t ws_size,
                              hipStream_t stream) {
  const float* x  = (const float*)d_in[0];
  const float* gw = (const float*)d_in[1];
  const float* w1 = (const float*)d_in[2];
  const float* b1 = (const float*)d_in[3];
  const float* w2 = (const float*)d_in[4];
  const float* b2 = (const float*)d_in[5];
  float* out = (float*)d_out;
  float* logits = out + (size_t)T_TOKENS * HID;

  char* ws = (char*)d_ws;
  int* nsched = (int*)ws;
  int* colbase = (int*)(ws + 64);
  int4* sched1  = (int4*)(ws + 512);               // <=264 entries
  int* tok_e01 = (int*)(ws + 16384);                              // 64 KB
  float2* tok_w = (float2*)(ws + 16384 + 65536);                  // 128 KB
  int* row_token = (int*)(ws + 16384 + 65536 + 131072);           // 128 KB
  float* row_weight = (float*)(ws + 16384 + 65536 + 2 * 131072);  // 128 KB
  int* bh  = (int*)(ws + 16384 + 65536 + 3 * 131072);             // 64 KB
  int* bhp = bh + 16384;                                          // 64 KB
  int2* tok_pos = (int2*)(ws + 16384 + 65536 + 3 * 131072 + 2 * 65536);  // 128 KB
  const size_t BIG = 1u << 20;
  unsigned short* xb  = (unsigned short*)(ws + BIG);  // 32 MiB
  unsigned short* w1b = xb  + (size_t)16777216;       // 32 MiB
  unsigned short* w2b = w1b + (size_t)16777216;       // 32 MiB
  unsigned short* h   = w2b + (size_t)16777216;       // 128 MiB
  // y (32768 x 1024 bf16 = 64 MiB) aliases [xb, w1b]: both dead after GEMM1
  unsigned short* y = xb;
  const size_t REQUIRED = BIG + 3ull * 33554432ull + 134217728ull;
  if (ws_size < REQUIRED) return;

  cast_bf16_kernel<<<2048, 256, 0, stream>>>(w1, w1b, 16777216);
  cast_bf16_kernel<<<2048, 256, 0, stream>>>(w2, w2b, 16777216);
  routing_kernel<<<1024, 256, 0, stream>>>(x, gw, logits, xb, bh, tok_e01, tok_w);
  sched_kernel<<<1, 1024, 0, stream>>>(bh, bhp, colbase, sched1, nsched);
  scatter_kernel<<<1024, 64, 0, stream>>>(tok_e01, tok_w, bhp, colbase,
                                          row_token, row_weight, tok_pos);
  // GEMM1: h = gelu(x @ w1^T + b1); <=263 row-tiles x 16 col-blocks
  gemm128_kernel<0, 1024, 2048><<<dim3(16, 264), 256, 0, stream>>>(
      xb, w1b, b1, h, row_token, nullptr, sched1, nsched);
  // GEMM2 single pass: y[row] = bf16(w*(h @ w2^T + b2)); 8 col-blocks
  gemm128_kernel<1, 2048, 1024><<<dim3(8, 264), 256, 0, stream>>>(
      h, w2b, b2, y, row_token, row_weight, sched1, nsched);
  // combine: out[t] = y[pos0(t)] + y[pos1(t)]
  combine_kernel<<<4096, 256, 0, stream>>>(y, tok_pos, out);
}

// Round 13
// 534.099 us; speedup vs baseline: 2.6263x; 1.1225x over previous
//
#include <hip/hip_runtime.h>
#include <stdint.h>

#define T_TOKENS 16384
#define HID 1024
#define INTERM 2048
#define NEXP 8

typedef __bf16 bf16x8 __attribute__((ext_vector_type(8)));
typedef float f32x4 __attribute__((ext_vector_type(4)));

// ---------- helpers ----------
__device__ __forceinline__ unsigned short f2bf(float f) {
  union { float f; uint32_t u; } v; v.f = f;
  uint32_t u = v.u + 0x7fffu + ((v.u >> 16) & 1u);
  return (unsigned short)(u >> 16);
}

__device__ __forceinline__ float bf2f(unsigned short u) {
  union { uint32_t u; float f; } v; v.u = ((uint32_t)u) << 16;
  return v.f;
}

__device__ __forceinline__ void async16(const void* g, void* l) {
  auto gp = (const __attribute__((address_space(1))) uint32_t*)(uintptr_t)g;
  auto lp = (__attribute__((address_space(3))) uint32_t*)(uintptr_t)l;
  __builtin_amdgcn_global_load_lds(gp, lp, 16, 0, 0);
}

// tanh-form gelu via fast exp: max abs err ~3e-4 vs exact erf-gelu
__device__ __forceinline__ float gelu_fast(float v) {
  float s = 1.5957691216f * v + 0.0713548163f * v * v * v;
  return v / (1.f + __expf(-s));
}

// ---------- fp32 -> bf16 cast (weights) ----------
__global__ void cast_bf16_kernel(const float* __restrict__ in,
                                 unsigned short* __restrict__ out, int n) {
  int stride = gridDim.x * blockDim.x;
  for (int i = blockIdx.x * blockDim.x + threadIdx.x; i < (n >> 2); i += stride) {
    float4 v = reinterpret_cast<const float4*>(in)[i];
    ushort4 o;
    o.x = f2bf(v.x); o.y = f2bf(v.y); o.z = f2bf(v.z); o.w = f2bf(v.w);
    reinterpret_cast<ushort4*>(out)[i] = o;
  }
}

// ---------- routing: wave/token dot, LDS histogram (NO global atomics) ----------
__global__ __launch_bounds__(256, 4) void routing_kernel(
    const float* __restrict__ x, const float* __restrict__ gw,
    float* __restrict__ logits, unsigned short* __restrict__ xb,
    int* __restrict__ bh, int* __restrict__ tok_e01, float2* __restrict__ tok_w) {
  __shared__ float4 gws[2048];  // 8 experts x 1024 floats = 32 KB
  __shared__ int lh[16];
  const int tid = threadIdx.x;
  if (tid < 16) lh[tid] = 0;
  for (int i = tid; i < 2048; i += 256)
    gws[i] = reinterpret_cast<const float4*>(gw)[i];
  __syncthreads();

  const int lane = tid & 63;
  const int wave = tid >> 6;
  const int tbase = blockIdx.x * 16 + wave * 4;
#pragma unroll 2
  for (int j = 0; j < 4; ++j) {
    int t = tbase + j;
    const float4* xr = reinterpret_cast<const float4*>(x + (size_t)t * HID);
    float4 xv[4];
#pragma unroll
    for (int q = 0; q < 4; ++q) xv[q] = xr[q * 64 + lane];
    ushort4* xbr = reinterpret_cast<ushort4*>(xb + (size_t)t * HID);
#pragma unroll
    for (int q = 0; q < 4; ++q) {
      ushort4 o;
      o.x = f2bf(xv[q].x); o.y = f2bf(xv[q].y);
      o.z = f2bf(xv[q].z); o.w = f2bf(xv[q].w);
      xbr[q * 64 + lane] = o;
    }
    float acc[NEXP];
#pragma unroll
    for (int e = 0; e < NEXP; ++e) {
      float a = 0.f;
#pragma unroll
      for (int q = 0; q < 4; ++q) {
        float4 g = gws[e * 256 + q * 64 + lane];
        a += xv[q].x * g.x + xv[q].y * g.y + xv[q].z * g.z + xv[q].w * g.w;
      }
      acc[e] = a;
    }
#pragma unroll
    for (int e = 0; e < NEXP; ++e)
#pragma unroll
      for (int off = 32; off > 0; off >>= 1)
        acc[e] += __shfl_xor(acc[e], off, 64);
    if (lane == 0) {
      int i0 = 0; float m0 = acc[0];
#pragma unroll
      for (int e = 1; e < NEXP; ++e) if (acc[e] > m0) { m0 = acc[e]; i0 = e; }
      int i1 = -1; float m1 = -3.4e38f;
#pragma unroll
      for (int e = 0; e < NEXP; ++e) if (e != i0 && acc[e] > m1) { m1 = acc[e]; i1 = e; }
      float w0 = 1.f / (1.f + expf(m1 - m0));
      float w1 = 1.f - w0;
      atomicAdd(&lh[i0], 1);
      atomicAdd(&lh[8 + i1], 1);
      tok_e01[t] = i0 | (i1 << 16);
      tok_w[t] = make_float2(w0, w1);
      float4* lg = reinterpret_cast<float4*>(logits + (size_t)t * NEXP);
      lg[0] = make_float4(acc[0], acc[1], acc[2], acc[3]);
      lg[1] = make_float4(acc[4], acc[5], acc[6], acc[7]);
    }
  }
  __syncthreads();
  if (tid < 16) bh[blockIdx.x * 16 + tid] = lh[tid];
}

// ---------- parallel schedule: column prefix scans + 128-row tile emission ----------
// Single tile list (expert-grouped rows) used by BOTH GEMMs.
__global__ __launch_bounds__(1024) void sched_kernel(
    const int* __restrict__ bh, int* __restrict__ bhp, int* __restrict__ colbase,
    int4* __restrict__ sched1, int* __restrict__ nsched) {
  const int tid = threadIdx.x;
  const int w = tid >> 6;
  const int lane = tid & 63;
  __shared__ int ct[16];
  __shared__ int offs[8];
  __shared__ int t1o[8];

  int carry = 0;
  for (int ch = 0; ch < 16; ++ch) {
    int b = ch * 64 + lane;
    int v = bh[b * 16 + w];
    int incl = v;
#pragma unroll
    for (int d = 1; d < 64; d <<= 1) {
      int tt = __shfl_up(incl, d, 64);
      if (lane >= d) incl += tt;
    }
    bhp[b * 16 + w] = incl - v + carry;
    carry += __shfl(incl, 63, 64);
  }
  if (lane == 0) ct[w] = carry;
  __syncthreads();
  if (tid == 0) {
    int o = 0, s1 = 0;
    for (int e = 0; e < NEXP; ++e) {
      offs[e] = o;
      int n = ct[e] + ct[8 + e];
      o += n;
      t1o[e] = s1;
      s1 += (n + 127) >> 7;
    }
    nsched[0] = s1;
  }
  __syncthreads();
  if (tid < 16) colbase[tid] = offs[tid & 7] + ((tid & 8) ? ct[tid & 7] : 0);
  if (tid < 8) {
    int e = tid;
    int n = ct[e] + ct[8 + e], o = offs[e];
    for (int i = 0, t0 = 0; t0 < n; t0 += 128, ++i) {
      int hi = t0 + 128 < n ? t0 + 128 : n;
      sched1[t1o[e] + i] = make_int4(o + t0, o + hi, e, 0);
    }
  }
}

// ---------- scatter: per-block LDS ranks + precomputed bases ----------
__global__ __launch_bounds__(64) void scatter_kernel(
    const int* __restrict__ tok_e01, const float2* __restrict__ tok_w,
    const int* __restrict__ bhp, const int* __restrict__ colbase,
    int* __restrict__ row_token, float* __restrict__ row_weight,
    int2* __restrict__ tok_pos) {
  __shared__ int lh[16];
  const int tid = threadIdx.x;
  if (tid < 16) lh[tid] = 0;
  __syncthreads();
  if (tid < 16) {
    int t = blockIdx.x * 16 + tid;
    int p = tok_e01[t];
    int e0 = p & 0xffff, e1 = p >> 16;
    float2 w = tok_w[t];
    int r0 = atomicAdd(&lh[e0], 1);
    int pos0 = colbase[e0] + bhp[blockIdx.x * 16 + e0] + r0;
    row_token[pos0] = t; row_weight[pos0] = w.x;
    int r1 = atomicAdd(&lh[8 + e1], 1);
    int pos1 = colbase[8 + e1] + bhp[blockIdx.x * 16 + 8 + e1] + r1;
    row_token[pos1] = t; row_weight[pos1] = w.y;
    tok_pos[t] = make_int2(pos0, pos1);
  }
}

// ---------- grouped GEMM 128x128xBK64, 4 waves, m97-structure ----------
// R9-proven config: __launch_bounds__(256,4) -> VGPR 64, occ 41% (best
// measured; R12's un-hinted (256) gave VGPR 80 -> occ 31%, slower; R10/R11's
// (256,5) gave VGPR 48 -> acc spill, 2.4x slower).
// 2D grid, col fastest: round-robin XCD dispatch pins XCD k to col-blocks
// {k, k+8} -> B partitioned across XCDs (L2-resident); A broadcasts via L3.
// T2 both-sides swizzle (bank conflicts 0, verified R5-R12).
// EPILOGUE (changed R13): n innermost + bias hoisted -> each 128 B row
// segment written in one tight window (R12 counters: n-outermost caused 2x
// HBM write amplification, WRITE 262 MB vs h's 134 MB).
// MODE 0: A gathered via row_token, epilogue gelu(.+b1) -> h (bf16)
// MODE 1: A = h rows (contiguous), epilogue y[row] = bf16(w*(acc+b2))
template <int MODE, int KDIM, int NDIM>
__global__ __launch_bounds__(256, 4) void gemm128_kernel(
    const unsigned short* __restrict__ A, const unsigned short* __restrict__ Bw,
    const float* __restrict__ bias, unsigned short* __restrict__ hOut,
    const int* __restrict__ row_token, const float* __restrict__ row_weight,
    const int4* __restrict__ sched, const int* __restrict__ nsched_p) {
  const int sid = blockIdx.y;  // blockIdx.x = col (fastest) -> XCD = col%8
  if (sid >= nsched_p[0]) return;
  int4 s = sched[sid];
  const int row_start = s.x, row_limit = s.y, e = s.z;
  const int colBase = blockIdx.x * 128;

  __shared__ __attribute__((aligned(16))) unsigned short As[128 * 64];  // 16 KB
  __shared__ __attribute__((aligned(16))) unsigned short Bs[128 * 64];  // 16 KB

  const int tid = threadIdx.x;
  const int wave = tid >> 6;
  const int lane = tid & 63;
  const int wr = wave >> 1;  // 0..1 (M half)
  const int wc = wave & 1;   // 0..1 (N half)

  // staging: thread covers (row = i*32 + tid>>3, phys chunk tid&7); T2 write
  // side fetches logical chunk (tid&7)^(row&7), row&7 == (tid>>3)&7
  const int schunk = (tid & 7) ^ ((tid >> 3) & 7);
  const unsigned short* aG[4];
  const unsigned short* bG[4];
  const unsigned short* Bbase = Bw + (size_t)e * ((size_t)NDIM * KDIM);
#pragma unroll
  for (int i = 0; i < 4; ++i) {
    int r = i * 32 + (tid >> 3);
    int rg = row_start + r;
    rg = rg < row_limit ? rg : (row_limit - 1);  // clamp partial tiles
    int arow = (MODE == 0) ? row_token[rg] : rg;
    aG[i] = A + (size_t)arow * KDIM + schunk * 8;
    bG[i] = Bbase + (size_t)(colBase + r) * KDIM + schunk * 8;
  }

  f32x4 zero = {0.f, 0.f, 0.f, 0.f};
  f32x4 acc[4][4];
#pragma unroll
  for (int m = 0; m < 4; ++m)
#pragma unroll
    for (int n = 0; n < 4; ++n) acc[m][n] = zero;

  const int rl = lane & 15;
  const int ch0 = lane >> 4;
  const int swz = rl & 7;
  const int cOff0 = (ch0 ^ swz) * 16;        // ks0 swizzled chunk byte
  const int cOff1 = ((4 + ch0) ^ swz) * 16;  // ks1
  const int arB = (wr * 64 + rl) * 128;      // A frag row-base byte (+m*2048)
  const int brB = (wc * 64 + rl) * 128;      // B frag row-base byte (+n*2048)

  for (int kt = 0; kt < KDIM / 64; ++kt) {
    if (kt) __syncthreads();  // all waves done reading previous tile
    const size_t koff = (size_t)kt * 64;  // elements (128 B)
#pragma unroll
    for (int i = 0; i < 4; ++i) {
      async16(aG[i] + koff, (char*)As + (i * 4 + wave) * 1024);
      async16(bG[i] + koff, (char*)Bs + (i * 4 + wave) * 1024);
    }
    __syncthreads();  // compiler drains vmcnt(0) before s_barrier: tile ready
#pragma unroll
    for (int ks = 0; ks < 2; ++ks) {
      const int co = ks ? cOff1 : cOff0;
      bf16x8 af[4], bfr[4];
#pragma unroll
      for (int m = 0; m < 4; ++m)
        af[m] = *reinterpret_cast<const bf16x8*>((const char*)As + arB + m * 2048 + co);
#pragma unroll
      for (int n = 0; n < 4; ++n)
        bfr[n] = *reinterpret_cast<const bf16x8*>((const char*)Bs + brB + n * 2048 + co);
#pragma unroll
      for (int m = 0; m < 4; ++m)
#pragma unroll
        for (int n = 0; n < 4; ++n)
          acc[m][n] = __builtin_amdgcn_mfma_f32_16x16x32_bf16(af[m], bfr[n], acc[m][n], 0, 0, 0);
    }
  }

  // epilogue: C/D map col=lane&15, row=(lane>>4)*4+j
  const int cCol = lane & 15;
  const int cRowB = (lane >> 4) * 4;

  // hoist per-lane bias values (4 cols, stride 16)
  float bb[4];
#pragma unroll
  for (int n = 0; n < 4; ++n)
    bb[n] = bias[e * NDIM + colBase + wc * 64 + n * 16 + cCol];

  if (MODE == 0) {
#pragma unroll
    for (int m = 0; m < 4; ++m) {
#pragma unroll
      for (int j = 0; j < 4; ++j) {
        int r = row_start + wr * 64 + m * 16 + cRowB + j;
        if (r < row_limit) {
          unsigned short* hrow = hOut + (size_t)r * NDIM + colBase + wc * 64 + cCol;
#pragma unroll
          for (int n = 0; n < 4; ++n)
            hrow[n * 16] = f2bf(gelu_fast(acc[m][n][j] + bb[n]));
        }
      }
    }
  } else {
#pragma unroll
    for (int m = 0; m < 4; ++m) {
#pragma unroll
      for (int j = 0; j < 4; ++j) {
        int rr = row_start + wr * 64 + m * 16 + cRowB + j;
        if (rr < row_limit) {
          float wgt = row_weight[rr];
          unsigned short* yrow = hOut + (size_t)rr * NDIM + colBase + wc * 64 + cCol;
#pragma unroll
          for (int n = 0; n < 4; ++n)
            yrow[n * 16] = f2bf(wgt * (acc[m][n][j] + bb[n]));
        }
      }
    }
  }
}

// ---------- combine: out[t] = y[pos0] + y[pos1] (wave per token, 16B ops) ----------
typedef unsigned short ushort8 __attribute__((ext_vector_type(8)));

__global__ __launch_bounds__(256) void combine_kernel(
    const unsigned short* __restrict__ y, const int2* __restrict__ tok_pos,
    float* __restrict__ out) {
  const int t = blockIdx.x * 4 + (threadIdx.x >> 6);
  const int lane = threadIdx.x & 63;
  int2 p = tok_pos[t];
  const ushort8* y0 = reinterpret_cast<const ushort8*>(y + (size_t)p.x * HID);
  const ushort8* y1 = reinterpret_cast<const ushort8*>(y + (size_t)p.y * HID);
  float4* o = reinterpret_cast<float4*>(out + (size_t)t * HID);
#pragma unroll
  for (int q = 0; q < 2; ++q) {
    ushort8 a = y0[q * 64 + lane];
    ushort8 b = y1[q * 64 + lane];
    float4 r0, r1;
    r0.x = bf2f(a[0]) + bf2f(b[0]);
    r0.y = bf2f(a[1]) + bf2f(b[1]);
    r0.z = bf2f(a[2]) + bf2f(b[2]);
    r0.w = bf2f(a[3]) + bf2f(b[3]);
    r1.x = bf2f(a[4]) + bf2f(b[4]);
    r1.y = bf2f(a[5]) + bf2f(b[5]);
    r1.z = bf2f(a[6]) + bf2f(b[6]);
    r1.w = bf2f(a[7]) + bf2f(b[7]);
    o[(q * 64 + lane) * 2] = r0;
    o[(q * 64 + lane) * 2 + 1] = r1;
  }
}

// ---------- launch ----------
extern "C" void kernel_launch(void* const* d_in, const int* in_sizes, int n_in,
                              void* d_out, int out_size, void* d_ws, size_t ws_size,
                              hipStream_t stream) {
  const float* x  = (const float*)d_in[0];
  const float* gw = (const float*)d_in[1];
  const float* w1 = (const float*)d_in[2];
  const float* b1 = (const float*)d_in[3];
  const float* w2 = (const float*)d_in[4];
  const float* b2 = (const float*)d_in[5];
  float* out = (float*)d_out;
  float* logits = out + (size_t)T_TOKENS * HID;

  char* ws = (char*)d_ws;
  int* nsched = (int*)ws;
  int* colbase = (int*)(ws + 64);
  int4* sched1  = (int4*)(ws + 512);               // <=264 entries
  int* tok_e01 = (int*)(ws + 16384);                              // 64 KB
  float2* tok_w = (float2*)(ws + 16384 + 65536);                  // 128 KB
  int* row_token = (int*)(ws + 16384 + 65536 + 131072);           // 128 KB
  float* row_weight = (float*)(ws + 16384 + 65536 + 2 * 131072);  // 128 KB
  int* bh  = (int*)(ws + 16384 + 65536 + 3 * 131072);             // 64 KB
  int* bhp = bh + 16384;                                          // 64 KB
  int2* tok_pos = (int2*)(ws + 16384 + 65536 + 3 * 131072 + 2 * 65536);  // 128 KB
  const size_t BIG = 1u << 20;
  unsigned short* xb  = (unsigned short*)(ws + BIG);  // 32 MiB
  unsigned short* w1b = xb  + (size_t)16777216;       // 32 MiB
  unsigned short* w2b = w1b + (size_t)16777216;       // 32 MiB
  unsigned short* h   = w2b + (size_t)16777216;       // 128 MiB
  // y (32768 x 1024 bf16 = 64 MiB) aliases [xb, w1b]: both dead after GEMM1
  unsigned short* y = xb;
  const size_t REQUIRED = BIG + 3ull * 33554432ull + 134217728ull;
  if (ws_size < REQUIRED) return;

  cast_bf16_kernel<<<2048, 256, 0, stream>>>(w1, w1b, 16777216);
  cast_bf16_kernel<<<2048, 256, 0, stream>>>(w2, w2b, 16777216);
  routing_kernel<<<1024, 256, 0, stream>>>(x, gw, logits, xb, bh, tok_e01, tok_w);
  sched_kernel<<<1, 1024, 0, stream>>>(bh, bhp, colbase, sched1, nsched);
  scatter_kernel<<<1024, 64, 0, stream>>>(tok_e01, tok_w, bhp, colbase,
                                          row_token, row_weight, tok_pos);
  // GEMM1: h = gelu(x @ w1^T + b1); <=263 row-tiles x 16 col-blocks
  gemm128_kernel<0, 1024, 2048><<<dim3(16, 264), 256, 0, stream>>>(
      xb, w1b, b1, h, row_token, nullptr, sched1, nsched);
  // GEMM2 single pass: y[row] = bf16(w*(h @ w2^T + b2)); 8 col-blocks
  gemm128_kernel<1, 2048, 1024><<<dim3(8, 264), 256, 0, stream>>>(
      h, w2b, b2, y, row_token, row_weight, sched1, nsched);
  // combine: out[t] = y[pos0(t)] + y[pos1(t)]
  combine_kernel<<<4096, 256, 0, stream>>>(y, tok_pos, out);
}

// Round 14
// 507.203 us; speedup vs baseline: 2.7655x; 1.0530x over previous
//
#include <hip/hip_runtime.h>
#include <stdint.h>

#define T_TOKENS 16384
#define HID 1024
#define INTERM 2048
#define NEXP 8

typedef __bf16 bf16x8 __attribute__((ext_vector_type(8)));
typedef float f32x4 __attribute__((ext_vector_type(4)));

// ---------- helpers ----------
__device__ __forceinline__ unsigned short f2bf(float f) {
  union { float f; uint32_t u; } v; v.f = f;
  uint32_t u = v.u + 0x7fffu + ((v.u >> 16) & 1u);
  return (unsigned short)(u >> 16);
}

__device__ __forceinline__ float bf2f(unsigned short u) {
  union { uint32_t u; float f; } v; v.u = ((uint32_t)u) << 16;
  return v.f;
}

__device__ __forceinline__ void async16(const void* g, void* l) {
  auto gp = (const __attribute__((address_space(1))) uint32_t*)(uintptr_t)g;
  auto lp = (__attribute__((address_space(3))) uint32_t*)(uintptr_t)l;
  __builtin_amdgcn_global_load_lds(gp, lp, 16, 0, 0);
}

// tanh-form gelu via fast exp: max abs err ~3e-4 vs exact erf-gelu
__device__ __forceinline__ float gelu_fast(float v) {
  float s = 1.5957691216f * v + 0.0713548163f * v * v * v;
  return v / (1.f + __expf(-s));
}

// ---------- fp32 -> bf16 cast (weights) ----------
__global__ void cast_bf16_kernel(const float* __restrict__ in,
                                 unsigned short* __restrict__ out, int n) {
  int stride = gridDim.x * blockDim.x;
  for (int i = blockIdx.x * blockDim.x + threadIdx.x; i < (n >> 2); i += stride) {
    float4 v = reinterpret_cast<const float4*>(in)[i];
    ushort4 o;
    o.x = f2bf(v.x); o.y = f2bf(v.y); o.z = f2bf(v.z); o.w = f2bf(v.w);
    reinterpret_cast<ushort4*>(out)[i] = o;
  }
}

// ---------- routing: wave/token dot, LDS histogram (NO global atomics) ----------
__global__ __launch_bounds__(256, 4) void routing_kernel(
    const float* __restrict__ x, const float* __restrict__ gw,
    float* __restrict__ logits, unsigned short* __restrict__ xb,
    int* __restrict__ bh, int* __restrict__ tok_e01, float2* __restrict__ tok_w) {
  __shared__ float4 gws[2048];  // 8 experts x 1024 floats = 32 KB
  __shared__ int lh[16];
  const int tid = threadIdx.x;
  if (tid < 16) lh[tid] = 0;
  for (int i = tid; i < 2048; i += 256)
    gws[i] = reinterpret_cast<const float4*>(gw)[i];
  __syncthreads();

  const int lane = tid & 63;
  const int wave = tid >> 6;
  const int tbase = blockIdx.x * 16 + wave * 4;
#pragma unroll 2
  for (int j = 0; j < 4; ++j) {
    int t = tbase + j;
    const float4* xr = reinterpret_cast<const float4*>(x + (size_t)t * HID);
    float4 xv[4];
#pragma unroll
    for (int q = 0; q < 4; ++q) xv[q] = xr[q * 64 + lane];
    ushort4* xbr = reinterpret_cast<ushort4*>(xb + (size_t)t * HID);
#pragma unroll
    for (int q = 0; q < 4; ++q) {
      ushort4 o;
      o.x = f2bf(xv[q].x); o.y = f2bf(xv[q].y);
      o.z = f2bf(xv[q].z); o.w = f2bf(xv[q].w);
      xbr[q * 64 + lane] = o;
    }
    float acc[NEXP];
#pragma unroll
    for (int e = 0; e < NEXP; ++e) {
      float a = 0.f;
#pragma unroll
      for (int q = 0; q < 4; ++q) {
        float4 g = gws[e * 256 + q * 64 + lane];
        a += xv[q].x * g.x + xv[q].y * g.y + xv[q].z * g.z + xv[q].w * g.w;
      }
      acc[e] = a;
    }
#pragma unroll
    for (int e = 0; e < NEXP; ++e)
#pragma unroll
      for (int off = 32; off > 0; off >>= 1)
        acc[e] += __shfl_xor(acc[e], off, 64);
    if (lane == 0) {
      int i0 = 0; float m0 = acc[0];
#pragma unroll
      for (int e = 1; e < NEXP; ++e) if (acc[e] > m0) { m0 = acc[e]; i0 = e; }
      int i1 = -1; float m1 = -3.4e38f;
#pragma unroll
      for (int e = 0; e < NEXP; ++e) if (e != i0 && acc[e] > m1) { m1 = acc[e]; i1 = e; }
      float w0 = 1.f / (1.f + expf(m1 - m0));
      float w1 = 1.f - w0;
      atomicAdd(&lh[i0], 1);
      atomicAdd(&lh[8 + i1], 1);
      tok_e01[t] = i0 | (i1 << 16);
      tok_w[t] = make_float2(w0, w1);
      float4* lg = reinterpret_cast<float4*>(logits + (size_t)t * NEXP);
      lg[0] = make_float4(acc[0], acc[1], acc[2], acc[3]);
      lg[1] = make_float4(acc[4], acc[5], acc[6], acc[7]);
    }
  }
  __syncthreads();
  if (tid < 16) bh[blockIdx.x * 16 + tid] = lh[tid];
}

// ---------- parallel schedule: column prefix scans + 128-row tile emission ----------
// Single tile list (expert-grouped rows) used by BOTH GEMMs.
__global__ __launch_bounds__(1024) void sched_kernel(
    const int* __restrict__ bh, int* __restrict__ bhp, int* __restrict__ colbase,
    int4* __restrict__ sched1, int* __restrict__ nsched) {
  const int tid = threadIdx.x;
  const int w = tid >> 6;
  const int lane = tid & 63;
  __shared__ int ct[16];
  __shared__ int offs[8];
  __shared__ int t1o[8];

  int carry = 0;
  for (int ch = 0; ch < 16; ++ch) {
    int b = ch * 64 + lane;
    int v = bh[b * 16 + w];
    int incl = v;
#pragma unroll
    for (int d = 1; d < 64; d <<= 1) {
      int tt = __shfl_up(incl, d, 64);
      if (lane >= d) incl += tt;
    }
    bhp[b * 16 + w] = incl - v + carry;
    carry += __shfl(incl, 63, 64);
  }
  if (lane == 0) ct[w] = carry;
  __syncthreads();
  if (tid == 0) {
    int o = 0, s1 = 0;
    for (int e = 0; e < NEXP; ++e) {
      offs[e] = o;
      int n = ct[e] + ct[8 + e];
      o += n;
      t1o[e] = s1;
      s1 += (n + 127) >> 7;
    }
    nsched[0] = s1;
  }
  __syncthreads();
  if (tid < 16) colbase[tid] = offs[tid & 7] + ((tid & 8) ? ct[tid & 7] : 0);
  if (tid < 8) {
    int e = tid;
    int n = ct[e] + ct[8 + e], o = offs[e];
    for (int i = 0, t0 = 0; t0 < n; t0 += 128, ++i) {
      int hi = t0 + 128 < n ? t0 + 128 : n;
      sched1[t1o[e] + i] = make_int4(o + t0, o + hi, e, 0);
    }
  }
}

// ---------- scatter: per-block LDS ranks + precomputed bases ----------
__global__ __launch_bounds__(64) void scatter_kernel(
    const int* __restrict__ tok_e01, const float2* __restrict__ tok_w,
    const int* __restrict__ bhp, const int* __restrict__ colbase,
    int* __restrict__ row_token, float* __restrict__ row_weight,
    int2* __restrict__ tok_pos) {
  __shared__ int lh[16];
  const int tid = threadIdx.x;
  if (tid < 16) lh[tid] = 0;
  __syncthreads();
  if (tid < 16) {
    int t = blockIdx.x * 16 + tid;
    int p = tok_e01[t];
    int e0 = p & 0xffff, e1 = p >> 16;
    float2 w = tok_w[t];
    int r0 = atomicAdd(&lh[e0], 1);
    int pos0 = colbase[e0] + bhp[blockIdx.x * 16 + e0] + r0;
    row_token[pos0] = t; row_weight[pos0] = w.x;
    int r1 = atomicAdd(&lh[8 + e1], 1);
    int pos1 = colbase[8 + e1] + bhp[blockIdx.x * 16 + 8 + e1] + r1;
    row_token[pos1] = t; row_weight[pos1] = w.y;
    tok_pos[t] = make_int2(pos0, pos1);
  }
}

// ---------- grouped GEMM 128x128xBK64, 4 waves, m97-structure ----------
// R9-proven occupancy config: __launch_bounds__(256,4) -> VGPR 64, ~5 blk/CU.
// T2 both-sides swizzle (bank conflicts 0, verified R5-R13).
// Epilogue n-innermost + hoisted bias (R13: fixed 2x write amplification).
// XCD MAP (changed R14): R13's col-fastest grid put each sid's col-blocks on
// ALL 8 XCDs -> A panel filled into 8 L2s: FETCH 575 MB = 264 sids x 8 x
// 256 KB. New bijective map pins each sid to 4 XCDs (CPX = NCOL/4 cols each,
// consecutive j -> concurrent -> one fill per XCD): A-fill halves (~340 MB).
// Working set per XCD: B slice CPX x 256 KB = 1 MB (fixed, L2-resident; R10's
// failure was the full 4 MB panel) + A K-tile windows ~1-2 MB < 4 MiB L2.
//   xcd = 4*(sid&1) + col/CPX;  j = (sid>>1)*CPX + col%CPX  (bijective)
// MODE 0: A gathered via row_token, epilogue gelu(.+b1) -> h (bf16)
// MODE 1: A = h rows (contiguous), epilogue y[row] = bf16(w*(acc+b2))
template <int MODE, int KDIM, int NDIM>
__global__ __launch_bounds__(256, 4) void gemm128_kernel(
    const unsigned short* __restrict__ A, const unsigned short* __restrict__ Bw,
    const float* __restrict__ bias, unsigned short* __restrict__ hOut,
    const int* __restrict__ row_token, const float* __restrict__ row_weight,
    const int4* __restrict__ sched, const int* __restrict__ nsched_p) {
  constexpr int NCOL = NDIM / 128;
  constexpr int CPX = NCOL / 4;  // col-blocks per XCD per sid
  const int xcd = blockIdx.x & 7;         // round-robin XCD assignment
  const int j = blockIdx.x >> 3;          // per-XCD block index
  const int sid = 2 * (j / CPX) + (xcd >> 2);
  const int colblk = (xcd & 3) * CPX + (j % CPX);
  if (sid >= nsched_p[0]) return;
  int4 s = sched[sid];
  const int row_start = s.x, row_limit = s.y, e = s.z;
  const int colBase = colblk * 128;

  __shared__ __attribute__((aligned(16))) unsigned short As[128 * 64];  // 16 KB
  __shared__ __attribute__((aligned(16))) unsigned short Bs[128 * 64];  // 16 KB

  const int tid = threadIdx.x;
  const int wave = tid >> 6;
  const int lane = tid & 63;
  const int wr = wave >> 1;  // 0..1 (M half)
  const int wc = wave & 1;   // 0..1 (N half)

  // staging: thread covers (row = i*32 + tid>>3, phys chunk tid&7); T2 write
  // side fetches logical chunk (tid&7)^(row&7), row&7 == (tid>>3)&7
  const int schunk = (tid & 7) ^ ((tid >> 3) & 7);
  const unsigned short* aG[4];
  const unsigned short* bG[4];
  const unsigned short* Bbase = Bw + (size_t)e * ((size_t)NDIM * KDIM);
#pragma unroll
  for (int i = 0; i < 4; ++i) {
    int r = i * 32 + (tid >> 3);
    int rg = row_start + r;
    rg = rg < row_limit ? rg : (row_limit - 1);  // clamp partial tiles
    int arow = (MODE == 0) ? row_token[rg] : rg;
    aG[i] = A + (size_t)arow * KDIM + schunk * 8;
    bG[i] = Bbase + (size_t)(colBase + r) * KDIM + schunk * 8;
  }

  f32x4 zero = {0.f, 0.f, 0.f, 0.f};
  f32x4 acc[4][4];
#pragma unroll
  for (int m = 0; m < 4; ++m)
#pragma unroll
    for (int n = 0; n < 4; ++n) acc[m][n] = zero;

  const int rl = lane & 15;
  const int ch0 = lane >> 4;
  const int swz = rl & 7;
  const int cOff0 = (ch0 ^ swz) * 16;        // ks0 swizzled chunk byte
  const int cOff1 = ((4 + ch0) ^ swz) * 16;  // ks1
  const int arB = (wr * 64 + rl) * 128;      // A frag row-base byte (+m*2048)
  const int brB = (wc * 64 + rl) * 128;      // B frag row-base byte (+n*2048)

  for (int kt = 0; kt < KDIM / 64; ++kt) {
    if (kt) __syncthreads();  // all waves done reading previous tile
    const size_t koff = (size_t)kt * 64;  // elements (128 B)
#pragma unroll
    for (int i = 0; i < 4; ++i) {
      async16(aG[i] + koff, (char*)As + (i * 4 + wave) * 1024);
      async16(bG[i] + koff, (char*)Bs + (i * 4 + wave) * 1024);
    }
    __syncthreads();  // compiler drains vmcnt(0) before s_barrier: tile ready
#pragma unroll
    for (int ks = 0; ks < 2; ++ks) {
      const int co = ks ? cOff1 : cOff0;
      bf16x8 af[4], bfr[4];
#pragma unroll
      for (int m = 0; m < 4; ++m)
        af[m] = *reinterpret_cast<const bf16x8*>((const char*)As + arB + m * 2048 + co);
#pragma unroll
      for (int n = 0; n < 4; ++n)
        bfr[n] = *reinterpret_cast<const bf16x8*>((const char*)Bs + brB + n * 2048 + co);
#pragma unroll
      for (int m = 0; m < 4; ++m)
#pragma unroll
        for (int n = 0; n < 4; ++n)
          acc[m][n] = __builtin_amdgcn_mfma_f32_16x16x32_bf16(af[m], bfr[n], acc[m][n], 0, 0, 0);
    }
  }

  // epilogue: C/D map col=lane&15, row=(lane>>4)*4+j
  const int cCol = lane & 15;
  const int cRowB = (lane >> 4) * 4;

  // hoist per-lane bias values (4 cols, stride 16)
  float bb[4];
#pragma unroll
  for (int n = 0; n < 4; ++n)
    bb[n] = bias[e * NDIM + colBase + wc * 64 + n * 16 + cCol];

  if (MODE == 0) {
#pragma unroll
    for (int m = 0; m < 4; ++m) {
#pragma unroll
      for (int jj = 0; jj < 4; ++jj) {
        int r = row_start + wr * 64 + m * 16 + cRowB + jj;
        if (r < row_limit) {
          unsigned short* hrow = hOut + (size_t)r * NDIM + colBase + wc * 64 + cCol;
#pragma unroll
          for (int n = 0; n < 4; ++n)
            hrow[n * 16] = f2bf(gelu_fast(acc[m][n][jj] + bb[n]));
        }
      }
    }
  } else {
#pragma unroll
    for (int m = 0; m < 4; ++m) {
#pragma unroll
      for (int jj = 0; jj < 4; ++jj) {
        int rr = row_start + wr * 64 + m * 16 + cRowB + jj;
        if (rr < row_limit) {
          float wgt = row_weight[rr];
          unsigned short* yrow = hOut + (size_t)rr * NDIM + colBase + wc * 64 + cCol;
#pragma unroll
          for (int n = 0; n < 4; ++n)
            yrow[n * 16] = f2bf(wgt * (acc[m][n][jj] + bb[n]));
        }
      }
    }
  }
}

// ---------- combine: out[t] = y[pos0] + y[pos1] (wave per token, 16B ops) ----------
typedef unsigned short ushort8 __attribute__((ext_vector_type(8)));

__global__ __launch_bounds__(256) void combine_kernel(
    const unsigned short* __restrict__ y, const int2* __restrict__ tok_pos,
    float* __restrict__ out) {
  const int t = blockIdx.x * 4 + (threadIdx.x >> 6);
  const int lane = threadIdx.x & 63;
  int2 p = tok_pos[t];
  const ushort8* y0 = reinterpret_cast<const ushort8*>(y + (size_t)p.x * HID);
  const ushort8* y1 = reinterpret_cast<const ushort8*>(y + (size_t)p.y * HID);
  float4* o = reinterpret_cast<float4*>(out + (size_t)t * HID);
#pragma unroll
  for (int q = 0; q < 2; ++q) {
    ushort8 a = y0[q * 64 + lane];
    ushort8 b = y1[q * 64 + lane];
    float4 r0, r1;
    r0.x = bf2f(a[0]) + bf2f(b[0]);
    r0.y = bf2f(a[1]) + bf2f(b[1]);
    r0.z = bf2f(a[2]) + bf2f(b[2]);
    r0.w = bf2f(a[3]) + bf2f(b[3]);
    r1.x = bf2f(a[4]) + bf2f(b[4]);
    r1.y = bf2f(a[5]) + bf2f(b[5]);
    r1.z = bf2f(a[6]) + bf2f(b[6]);
    r1.w = bf2f(a[7]) + bf2f(b[7]);
    o[(q * 64 + lane) * 2] = r0;
    o[(q * 64 + lane) * 2 + 1] = r1;
  }
}

// ---------- launch ----------
extern "C" void kernel_launch(void* const* d_in, const int* in_sizes, int n_in,
                              void* d_out, int out_size, void* d_ws, size_t ws_size,
                              hipStream_t stream) {
  const float* x  = (const float*)d_in[0];
  const float* gw = (const float*)d_in[1];
  const float* w1 = (const float*)d_in[2];
  const float* b1 = (const float*)d_in[3];
  const float* w2 = (const float*)d_in[4];
  const float* b2 = (const float*)d_in[5];
  float* out = (float*)d_out;
  float* logits = out + (size_t)T_TOKENS * HID;

  char* ws = (char*)d_ws;
  int* nsched = (int*)ws;
  int* colbase = (int*)(ws + 64);
  int4* sched1  = (int4*)(ws + 512);               // <=264 entries
  int* tok_e01 = (int*)(ws + 16384);                              // 64 KB
  float2* tok_w = (float2*)(ws + 16384 + 65536);                  // 128 KB
  int* row_token = (int*)(ws + 16384 + 65536 + 131072);           // 128 KB
  float* row_weight = (float*)(ws + 16384 + 65536 + 2 * 131072);  // 128 KB
  int* bh  = (int*)(ws + 16384 + 65536 + 3 * 131072);             // 64 KB
  int* bhp = bh + 16384;                                          // 64 KB
  int2* tok_pos = (int2*)(ws + 16384 + 65536 + 3 * 131072 + 2 * 65536);  // 128 KB
  const size_t BIG = 1u << 20;
  unsigned short* xb  = (unsigned short*)(ws + BIG);  // 32 MiB
  unsigned short* w1b = xb  + (size_t)16777216;       // 32 MiB
  unsigned short* w2b = w1b + (size_t)16777216;       // 32 MiB
  unsigned short* h   = w2b + (size_t)16777216;       // 128 MiB
  // y (32768 x 1024 bf16 = 64 MiB) aliases [xb, w1b]: both dead after GEMM1
  unsigned short* y = xb;
  const size_t REQUIRED = BIG + 3ull * 33554432ull + 134217728ull;
  if (ws_size < REQUIRED) return;

  cast_bf16_kernel<<<2048, 256, 0, stream>>>(w1, w1b, 16777216);
  cast_bf16_kernel<<<2048, 256, 0, stream>>>(w2, w2b, 16777216);
  routing_kernel<<<1024, 256, 0, stream>>>(x, gw, logits, xb, bh, tok_e01, tok_w);
  sched_kernel<<<1, 1024, 0, stream>>>(bh, bhp, colbase, sched1, nsched);
  scatter_kernel<<<1024, 64, 0, stream>>>(tok_e01, tok_w, bhp, colbase,
                                          row_token, row_weight, tok_pos);
  // GEMM1: h = gelu(x @ w1^T + b1); flat 4224 = 8 xcd x 132 x CPX(4)
  gemm128_kernel<0, 1024, 2048><<<4224, 256, 0, stream>>>(
      xb, w1b, b1, h, row_token, nullptr, sched1, nsched);
  // GEMM2 single pass: y[row] = bf16(w*(h @ w2^T + b2)); flat 2112 = 8 x 132 x CPX(2)
  gemm128_kernel<1, 2048, 1024><<<2112, 256, 0, stream>>>(
      h, w2b, b2, y, row_token, row_weight, sched1, nsched);
  // combine: out[t] = y[pos0(t)] + y[pos1(t)]
  combine_kernel<<<4096, 256, 0, stream>>>(y, tok_pos, out);
}

// Round 15
// 501.305 us; speedup vs baseline: 2.7981x; 1.0118x over previous
//
#include <hip/hip_runtime.h>
#include <stdint.h>

#define T_TOKENS 16384
#define HID 1024
#define INTERM 2048
#define NEXP 8

typedef __bf16 bf16x8 __attribute__((ext_vector_type(8)));
typedef float f32x4 __attribute__((ext_vector_type(4)));

// ---------- helpers ----------
__device__ __forceinline__ unsigned short f2bf(float f) {
  union { float f; uint32_t u; } v; v.f = f;
  uint32_t u = v.u + 0x7fffu + ((v.u >> 16) & 1u);
  return (unsigned short)(u >> 16);
}

__device__ __forceinline__ float bf2f(unsigned short u) {
  union { uint32_t u; float f; } v; v.u = ((uint32_t)u) << 16;
  return v.f;
}

__device__ __forceinline__ void async16(const void* g, void* l) {
  auto gp = (const __attribute__((address_space(1))) uint32_t*)(uintptr_t)g;
  auto lp = (__attribute__((address_space(3))) uint32_t*)(uintptr_t)l;
  __builtin_amdgcn_global_load_lds(gp, lp, 16, 0, 0);
}

// tanh-form gelu via fast exp: max abs err ~3e-4 vs exact erf-gelu
__device__ __forceinline__ float gelu_fast(float v) {
  float s = 1.5957691216f * v + 0.0713548163f * v * v * v;
  return v / (1.f + __expf(-s));
}

// ---------- fp32 -> bf16 cast (both weight tensors, one launch) ----------
__global__ void cast2_bf16_kernel(const float* __restrict__ a, unsigned short* __restrict__ ab,
                                  const float* __restrict__ b, unsigned short* __restrict__ bb,
                                  int n) {  // n = elements per tensor
  int stride = gridDim.x * blockDim.x;
  int q = n >> 2;
  for (int i = blockIdx.x * blockDim.x + threadIdx.x; i < q; i += stride) {
    float4 v = reinterpret_cast<const float4*>(a)[i];
    ushort4 o;
    o.x = f2bf(v.x); o.y = f2bf(v.y); o.z = f2bf(v.z); o.w = f2bf(v.w);
    reinterpret_cast<ushort4*>(ab)[i] = o;
  }
  for (int i = blockIdx.x * blockDim.x + threadIdx.x; i < q; i += stride) {
    float4 v = reinterpret_cast<const float4*>(b)[i];
    ushort4 o;
    o.x = f2bf(v.x); o.y = f2bf(v.y); o.z = f2bf(v.z); o.w = f2bf(v.w);
    reinterpret_cast<ushort4*>(bb)[i] = o;
  }
}

// ---------- routing: wave/token dot, LDS histogram (NO global atomics) ----------
__global__ __launch_bounds__(256, 4) void routing_kernel(
    const float* __restrict__ x, const float* __restrict__ gw,
    float* __restrict__ logits, unsigned short* __restrict__ xb,
    int* __restrict__ bh, int* __restrict__ tok_e01, float2* __restrict__ tok_w) {
  __shared__ float4 gws[2048];  // 8 experts x 1024 floats = 32 KB
  __shared__ int lh[16];
  const int tid = threadIdx.x;
  if (tid < 16) lh[tid] = 0;
  for (int i = tid; i < 2048; i += 256)
    gws[i] = reinterpret_cast<const float4*>(gw)[i];
  __syncthreads();

  const int lane = tid & 63;
  const int wave = tid >> 6;
  const int tbase = blockIdx.x * 16 + wave * 4;
#pragma unroll 2
  for (int j = 0; j < 4; ++j) {
    int t = tbase + j;
    const float4* xr = reinterpret_cast<const float4*>(x + (size_t)t * HID);
    float4 xv[4];
#pragma unroll
    for (int q = 0; q < 4; ++q) xv[q] = xr[q * 64 + lane];
    ushort4* xbr = reinterpret_cast<ushort4*>(xb + (size_t)t * HID);
#pragma unroll
    for (int q = 0; q < 4; ++q) {
      ushort4 o;
      o.x = f2bf(xv[q].x); o.y = f2bf(xv[q].y);
      o.z = f2bf(xv[q].z); o.w = f2bf(xv[q].w);
      xbr[q * 64 + lane] = o;
    }
    float acc[NEXP];
#pragma unroll
    for (int e = 0; e < NEXP; ++e) {
      float a = 0.f;
#pragma unroll
      for (int q = 0; q < 4; ++q) {
        float4 g = gws[e * 256 + q * 64 + lane];
        a += xv[q].x * g.x + xv[q].y * g.y + xv[q].z * g.z + xv[q].w * g.w;
      }
      acc[e] = a;
    }
#pragma unroll
    for (int e = 0; e < NEXP; ++e)
#pragma unroll
      for (int off = 32; off > 0; off >>= 1)
        acc[e] += __shfl_xor(acc[e], off, 64);
    if (lane == 0) {
      int i0 = 0; float m0 = acc[0];
#pragma unroll
      for (int e = 1; e < NEXP; ++e) if (acc[e] > m0) { m0 = acc[e]; i0 = e; }
      int i1 = -1; float m1 = -3.4e38f;
#pragma unroll
      for (int e = 0; e < NEXP; ++e) if (e != i0 && acc[e] > m1) { m1 = acc[e]; i1 = e; }
      float w0 = 1.f / (1.f + expf(m1 - m0));
      float w1 = 1.f - w0;
      atomicAdd(&lh[i0], 1);
      atomicAdd(&lh[8 + i1], 1);
      tok_e01[t] = i0 | (i1 << 16);
      tok_w[t] = make_float2(w0, w1);
      float4* lg = reinterpret_cast<float4*>(logits + (size_t)t * NEXP);
      lg[0] = make_float4(acc[0], acc[1], acc[2], acc[3]);
      lg[1] = make_float4(acc[4], acc[5], acc[6], acc[7]);
    }
  }
  __syncthreads();
  if (tid < 16) bh[blockIdx.x * 16 + tid] = lh[tid];
}

// ---------- parallel schedule: column prefix scans + 128-row tile emission ----------
// Single tile list (expert-grouped rows) used by BOTH GEMMs.
__global__ __launch_bounds__(1024) void sched_kernel(
    const int* __restrict__ bh, int* __restrict__ bhp, int* __restrict__ colbase,
    int4* __restrict__ sched1, int* __restrict__ nsched) {
  const int tid = threadIdx.x;
  const int w = tid >> 6;
  const int lane = tid & 63;
  __shared__ int ct[16];
  __shared__ int offs[8];
  __shared__ int t1o[8];

  int carry = 0;
  for (int ch = 0; ch < 16; ++ch) {
    int b = ch * 64 + lane;
    int v = bh[b * 16 + w];
    int incl = v;
#pragma unroll
    for (int d = 1; d < 64; d <<= 1) {
      int tt = __shfl_up(incl, d, 64);
      if (lane >= d) incl += tt;
    }
    bhp[b * 16 + w] = incl - v + carry;
    carry += __shfl(incl, 63, 64);
  }
  if (lane == 0) ct[w] = carry;
  __syncthreads();
  if (tid == 0) {
    int o = 0, s1 = 0;
    for (int e = 0; e < NEXP; ++e) {
      offs[e] = o;
      int n = ct[e] + ct[8 + e];
      o += n;
      t1o[e] = s1;
      s1 += (n + 127) >> 7;
    }
    nsched[0] = s1;
  }
  __syncthreads();
  if (tid < 16) colbase[tid] = offs[tid & 7] + ((tid & 8) ? ct[tid & 7] : 0);
  if (tid < 8) {
    int e = tid;
    int n = ct[e] + ct[8 + e], o = offs[e];
    for (int i = 0, t0 = 0; t0 < n; t0 += 128, ++i) {
      int hi = t0 + 128 < n ? t0 + 128 : n;
      sched1[t1o[e] + i] = make_int4(o + t0, o + hi, e, 0);
    }
  }
}

// ---------- scatter: per-block LDS ranks + precomputed bases ----------
__global__ __launch_bounds__(64) void scatter_kernel(
    const int* __restrict__ tok_e01, const float2* __restrict__ tok_w,
    const int* __restrict__ bhp, const int* __restrict__ colbase,
    int* __restrict__ row_token, float* __restrict__ row_weight,
    int2* __restrict__ tok_pos) {
  __shared__ int lh[16];
  const int tid = threadIdx.x;
  if (tid < 16) lh[tid] = 0;
  __syncthreads();
  if (tid < 16) {
    int t = blockIdx.x * 16 + tid;
    int p = tok_e01[t];
    int e0 = p & 0xffff, e1 = p >> 16;
    float2 w = tok_w[t];
    int r0 = atomicAdd(&lh[e0], 1);
    int pos0 = colbase[e0] + bhp[blockIdx.x * 16 + e0] + r0;
    row_token[pos0] = t; row_weight[pos0] = w.x;
    int r1 = atomicAdd(&lh[8 + e1], 1);
    int pos1 = colbase[8 + e1] + bhp[blockIdx.x * 16 + 8 + e1] + r1;
    row_token[pos1] = t; row_weight[pos1] = w.y;
    tok_pos[t] = make_int2(pos0, pos1);
  }
}

// ---------- grouped GEMM 128x128xBK64, 4 waves, m97-structure ----------
// R9-proven occupancy config: __launch_bounds__(256,4) -> VGPR 64, ~5 blk/CU.
// T2 both-sides swizzle (bank conflicts 0, verified R5-R14).
// Epilogue n-innermost + hoisted bias (R13: fixed 2x write amplification).
// XCD MAP (changed R15): 2 XCDs per sid (was 4). R14 fill model verified
// predictive (GEMM1: 264 A + 64 w1 = 328 ~= 336 measured). Halving XCD
// spread halves the A/h panel fill: GEMM1 ~260 MB, GEMM2 536->~332 MB
// (h was filled 4x -> 2x; GEMM2's K-amortization advantage restored).
// Working set per XCD: GEMM1 B slice 8 cols = 2 MB, GEMM2 1 MB (+ streamed
// A) < 4 MiB L2. (R10's failure needed the full 4 MB panel resident.)
//   xcd = 2*(sid&3) + col/HC;  j = (sid>>2)*HC + col%HC  (HC=NCOL/2, bijective)
// MODE 0: A gathered via row_token, epilogue gelu(.+b1) -> h (bf16)
// MODE 1: A = h rows (contiguous), epilogue y[row] = bf16(w*(acc+b2))
template <int MODE, int KDIM, int NDIM>
__global__ __launch_bounds__(256, 4) void gemm128_kernel(
    const unsigned short* __restrict__ A, const unsigned short* __restrict__ Bw,
    const float* __restrict__ bias, unsigned short* __restrict__ hOut,
    const int* __restrict__ row_token, const float* __restrict__ row_weight,
    const int4* __restrict__ sched, const int* __restrict__ nsched_p) {
  constexpr int NCOL = NDIM / 128;
  constexpr int HC = NCOL / 2;            // col-blocks per XCD per sid
  const int xcd = blockIdx.x & 7;         // round-robin XCD assignment
  const int j = blockIdx.x >> 3;          // per-XCD block index
  const int sid = 4 * (j / HC) + (xcd >> 1);
  const int colblk = (xcd & 1) * HC + (j % HC);
  if (sid >= nsched_p[0]) return;
  int4 s = sched[sid];
  const int row_start = s.x, row_limit = s.y, e = s.z;
  const int colBase = colblk * 128;

  __shared__ __attribute__((aligned(16))) unsigned short As[128 * 64];  // 16 KB
  __shared__ __attribute__((aligned(16))) unsigned short Bs[128 * 64];  // 16 KB

  const int tid = threadIdx.x;
  const int wave = tid >> 6;
  const int lane = tid & 63;
  const int wr = wave >> 1;  // 0..1 (M half)
  const int wc = wave & 1;   // 0..1 (N half)

  // staging: thread covers (row = i*32 + tid>>3, phys chunk tid&7); T2 write
  // side fetches logical chunk (tid&7)^(row&7), row&7 == (tid>>3)&7
  const int schunk = (tid & 7) ^ ((tid >> 3) & 7);
  const unsigned short* aG[4];
  const unsigned short* bG[4];
  const unsigned short* Bbase = Bw + (size_t)e * ((size_t)NDIM * KDIM);
#pragma unroll
  for (int i = 0; i < 4; ++i) {
    int r = i * 32 + (tid >> 3);
    int rg = row_start + r;
    rg = rg < row_limit ? rg : (row_limit - 1);  // clamp partial tiles
    int arow = (MODE == 0) ? row_token[rg] : rg;
    aG[i] = A + (size_t)arow * KDIM + schunk * 8;
    bG[i] = Bbase + (size_t)(colBase + r) * KDIM + schunk * 8;
  }

  f32x4 zero = {0.f, 0.f, 0.f, 0.f};
  f32x4 acc[4][4];
#pragma unroll
  for (int m = 0; m < 4; ++m)
#pragma unroll
    for (int n = 0; n < 4; ++n) acc[m][n] = zero;

  const int rl = lane & 15;
  const int ch0 = lane >> 4;
  const int swz = rl & 7;
  const int cOff0 = (ch0 ^ swz) * 16;        // ks0 swizzled chunk byte
  const int cOff1 = ((4 + ch0) ^ swz) * 16;  // ks1
  const int arB = (wr * 64 + rl) * 128;      // A frag row-base byte (+m*2048)
  const int brB = (wc * 64 + rl) * 128;      // B frag row-base byte (+n*2048)

  for (int kt = 0; kt < KDIM / 64; ++kt) {
    if (kt) __syncthreads();  // all waves done reading previous tile
    const size_t koff = (size_t)kt * 64;  // elements (128 B)
#pragma unroll
    for (int i = 0; i < 4; ++i) {
      async16(aG[i] + koff, (char*)As + (i * 4 + wave) * 1024);
      async16(bG[i] + koff, (char*)Bs + (i * 4 + wave) * 1024);
    }
    __syncthreads();  // compiler drains vmcnt(0) before s_barrier: tile ready
#pragma unroll
    for (int ks = 0; ks < 2; ++ks) {
      const int co = ks ? cOff1 : cOff0;
      bf16x8 af[4], bfr[4];
#pragma unroll
      for (int m = 0; m < 4; ++m)
        af[m] = *reinterpret_cast<const bf16x8*>((const char*)As + arB + m * 2048 + co);
#pragma unroll
      for (int n = 0; n < 4; ++n)
        bfr[n] = *reinterpret_cast<const bf16x8*>((const char*)Bs + brB + n * 2048 + co);
#pragma unroll
      for (int m = 0; m < 4; ++m)
#pragma unroll
        for (int n = 0; n < 4; ++n)
          acc[m][n] = __builtin_amdgcn_mfma_f32_16x16x32_bf16(af[m], bfr[n], acc[m][n], 0, 0, 0);
    }
  }

  // epilogue: C/D map col=lane&15, row=(lane>>4)*4+j
  const int cCol = lane & 15;
  const int cRowB = (lane >> 4) * 4;

  // hoist per-lane bias values (4 cols, stride 16)
  float bb[4];
#pragma unroll
  for (int n = 0; n < 4; ++n)
    bb[n] = bias[e * NDIM + colBase + wc * 64 + n * 16 + cCol];

  if (MODE == 0) {
#pragma unroll
    for (int m = 0; m < 4; ++m) {
#pragma unroll
      for (int jj = 0; jj < 4; ++jj) {
        int r = row_start + wr * 64 + m * 16 + cRowB + jj;
        if (r < row_limit) {
          unsigned short* hrow = hOut + (size_t)r * NDIM + colBase + wc * 64 + cCol;
#pragma unroll
          for (int n = 0; n < 4; ++n)
            hrow[n * 16] = f2bf(gelu_fast(acc[m][n][jj] + bb[n]));
        }
      }
    }
  } else {
#pragma unroll
    for (int m = 0; m < 4; ++m) {
#pragma unroll
      for (int jj = 0; jj < 4; ++jj) {
        int rr = row_start + wr * 64 + m * 16 + cRowB + jj;
        if (rr < row_limit) {
          float wgt = row_weight[rr];
          unsigned short* yrow = hOut + (size_t)rr * NDIM + colBase + wc * 64 + cCol;
#pragma unroll
          for (int n = 0; n < 4; ++n)
            yrow[n * 16] = f2bf(wgt * (acc[m][n][jj] + bb[n]));
        }
      }
    }
  }
}

// ---------- combine: out[t] = y[pos0] + y[pos1] (wave per token, 16B ops) ----------
typedef unsigned short ushort8 __attribute__((ext_vector_type(8)));

__global__ __launch_bounds__(256) void combine_kernel(
    const unsigned short* __restrict__ y, const int2* __restrict__ tok_pos,
    float* __restrict__ out) {
  const int t = blockIdx.x * 4 + (threadIdx.x >> 6);
  const int lane = threadIdx.x & 63;
  int2 p = tok_pos[t];
  const ushort8* y0 = reinterpret_cast<const ushort8*>(y + (size_t)p.x * HID);
  const ushort8* y1 = reinterpret_cast<const ushort8*>(y + (size_t)p.y * HID);
  float4* o = reinterpret_cast<float4*>(out + (size_t)t * HID);
#pragma unroll
  for (int q = 0; q < 2; ++q) {
    ushort8 a = y0[q * 64 + lane];
    ushort8 b = y1[q * 64 + lane];
    float4 r0, r1;
    r0.x = bf2f(a[0]) + bf2f(b[0]);
    r0.y = bf2f(a[1]) + bf2f(b[1]);
    r0.z = bf2f(a[2]) + bf2f(b[2]);
    r0.w = bf2f(a[3]) + bf2f(b[3]);
    r1.x = bf2f(a[4]) + bf2f(b[4]);
    r1.y = bf2f(a[5]) + bf2f(b[5]);
    r1.z = bf2f(a[6]) + bf2f(b[6]);
    r1.w = bf2f(a[7]) + bf2f(b[7]);
    o[(q * 64 + lane) * 2] = r0;
    o[(q * 64 + lane) * 2 + 1] = r1;
  }
}

// ---------- launch ----------
extern "C" void kernel_launch(void* const* d_in, const int* in_sizes, int n_in,
                              void* d_out, int out_size, void* d_ws, size_t ws_size,
                              hipStream_t stream) {
  const float* x  = (const float*)d_in[0];
  const float* gw = (const float*)d_in[1];
  const float* w1 = (const float*)d_in[2];
  const float* b1 = (const float*)d_in[3];
  const float* w2 = (const float*)d_in[4];
  const float* b2 = (const float*)d_in[5];
  float* out = (float*)d_out;
  float* logits = out + (size_t)T_TOKENS * HID;

  char* ws = (char*)d_ws;
  int* nsched = (int*)ws;
  int* colbase = (int*)(ws + 64);
  int4* sched1  = (int4*)(ws + 512);               // <=264 entries
  int* tok_e01 = (int*)(ws + 16384);                              // 64 KB
  float2* tok_w = (float2*)(ws + 16384 + 65536);                  // 128 KB
  int* row_token = (int*)(ws + 16384 + 65536 + 131072);           // 128 KB
  float* row_weight = (float*)(ws + 16384 + 65536 + 2 * 131072);  // 128 KB
  int* bh  = (int*)(ws + 16384 + 65536 + 3 * 131072);             // 64 KB
  int* bhp = bh + 16384;                                          // 64 KB
  int2* tok_pos = (int2*)(ws + 16384 + 65536 + 3 * 131072 + 2 * 65536);  // 128 KB
  const size_t BIG = 1u << 20;
  unsigned short* xb  = (unsigned short*)(ws + BIG);  // 32 MiB
  unsigned short* w1b = xb  + (size_t)16777216;       // 32 MiB
  unsigned short* w2b = w1b + (size_t)16777216;       // 32 MiB
  unsigned short* h   = w2b + (size_t)16777216;       // 128 MiB
  // y (32768 x 1024 bf16 = 64 MiB) aliases [xb, w1b]: both dead after GEMM1
  unsigned short* y = xb;
  const size_t REQUIRED = BIG + 3ull * 33554432ull + 134217728ull;
  if (ws_size < REQUIRED) return;

  cast2_bf16_kernel<<<2048, 256, 0, stream>>>(w1, w1b, w2, w2b, 16777216);
  routing_kernel<<<1024, 256, 0, stream>>>(x, gw, logits, xb, bh, tok_e01, tok_w);
  sched_kernel<<<1, 1024, 0, stream>>>(bh, bhp, colbase, sched1, nsched);
  scatter_kernel<<<1024, 64, 0, stream>>>(tok_e01, tok_w, bhp, colbase,
                                          row_token, row_weight, tok_pos);
  // GEMM1: h = gelu(x @ w1^T + b1); flat 4224 = 8 xcd x 66 groups x HC(8)
  gemm128_kernel<0, 1024, 2048><<<4224, 256, 0, stream>>>(
      xb, w1b, b1, h, row_token, nullptr, sched1, nsched);
  // GEMM2 single pass: y[row] = bf16(w*(h @ w2^T + b2)); 2112 = 8 x 66 x HC(4)
  gemm128_kernel<1, 2048, 1024><<<2112, 256, 0, stream>>>(
      h, w2b, b2, y, row_token, row_weight, sched1, nsched);
  // combine: out[t] = y[pos0(t)] + y[pos1(t)]
  combine_kernel<<<4096, 256, 0, stream>>>(y, tok_pos, out);
}

// Round 16
// 496.740 us; speedup vs baseline: 2.8238x; 1.0092x over previous
//
#include <hip/hip_runtime.h>
#include <stdint.h>

#define T_TOKENS 16384
#define HID 1024
#define INTERM 2048
#define NEXP 8

typedef __bf16 bf16x8 __attribute__((ext_vector_type(8)));
typedef float f32x4 __attribute__((ext_vector_type(4)));

// ---------- helpers ----------
__device__ __forceinline__ unsigned short f2bf(float f) {
  union { float f; uint32_t u; } v; v.f = f;
  uint32_t u = v.u + 0x7fffu + ((v.u >> 16) & 1u);
  return (unsigned short)(u >> 16);
}

__device__ __forceinline__ float bf2f(unsigned short u) {
  union { uint32_t u; float f; } v; v.u = ((uint32_t)u) << 16;
  return v.f;
}

__device__ __forceinline__ void async16(const void* g, void* l) {
  auto gp = (const __attribute__((address_space(1))) uint32_t*)(uintptr_t)g;
  auto lp = (__attribute__((address_space(3))) uint32_t*)(uintptr_t)l;
  __builtin_amdgcn_global_load_lds(gp, lp, 16, 0, 0);
}

// tanh-form gelu via fast exp: max abs err ~3e-4 vs exact erf-gelu
__device__ __forceinline__ float gelu_fast(float v) {
  float s = 1.5957691216f * v + 0.0713548163f * v * v * v;
  return v / (1.f + __expf(-s));
}

// ---------- routing + fused x->bf16 cast + fused WEIGHT cast ----------
// The w1/w2 cast is independent of all routing work; as a grid-stride tail it
// overlaps with other blocks' token phases instead of serializing as its own
// dispatch (R15: cast2 ~55-65 us + routing ~40 us serial -> fused ~55-70 us).
__global__ __launch_bounds__(256, 4) void routing_kernel(
    const float* __restrict__ x, const float* __restrict__ gw,
    float* __restrict__ logits, unsigned short* __restrict__ xb,
    int* __restrict__ bh, int* __restrict__ tok_e01, float2* __restrict__ tok_w,
    const float* __restrict__ w1, unsigned short* __restrict__ w1b,
    const float* __restrict__ w2, unsigned short* __restrict__ w2b) {
  __shared__ float4 gws[2048];  // 8 experts x 1024 floats = 32 KB
  __shared__ int lh[16];
  const int tid = threadIdx.x;
  if (tid < 16) lh[tid] = 0;
  for (int i = tid; i < 2048; i += 256)
    gws[i] = reinterpret_cast<const float4*>(gw)[i];
  __syncthreads();

  const int lane = tid & 63;
  const int wave = tid >> 6;
  const int tbase = blockIdx.x * 16 + wave * 4;
#pragma unroll 2
  for (int j = 0; j < 4; ++j) {
    int t = tbase + j;
    const float4* xr = reinterpret_cast<const float4*>(x + (size_t)t * HID);
    float4 xv[4];
#pragma unroll
    for (int q = 0; q < 4; ++q) xv[q] = xr[q * 64 + lane];
    ushort4* xbr = reinterpret_cast<ushort4*>(xb + (size_t)t * HID);
#pragma unroll
    for (int q = 0; q < 4; ++q) {
      ushort4 o;
      o.x = f2bf(xv[q].x); o.y = f2bf(xv[q].y);
      o.z = f2bf(xv[q].z); o.w = f2bf(xv[q].w);
      xbr[q * 64 + lane] = o;
    }
    float acc[NEXP];
#pragma unroll
    for (int e = 0; e < NEXP; ++e) {
      float a = 0.f;
#pragma unroll
      for (int q = 0; q < 4; ++q) {
        float4 g = gws[e * 256 + q * 64 + lane];
        a += xv[q].x * g.x + xv[q].y * g.y + xv[q].z * g.z + xv[q].w * g.w;
      }
      acc[e] = a;
    }
#pragma unroll
    for (int e = 0; e < NEXP; ++e)
#pragma unroll
      for (int off = 32; off > 0; off >>= 1)
        acc[e] += __shfl_xor(acc[e], off, 64);
    if (lane == 0) {
      int i0 = 0; float m0 = acc[0];
#pragma unroll
      for (int e = 1; e < NEXP; ++e) if (acc[e] > m0) { m0 = acc[e]; i0 = e; }
      int i1 = -1; float m1 = -3.4e38f;
#pragma unroll
      for (int e = 0; e < NEXP; ++e) if (e != i0 && acc[e] > m1) { m1 = acc[e]; i1 = e; }
      float w0 = 1.f / (1.f + expf(m1 - m0));
      float w1s = 1.f - w0;
      atomicAdd(&lh[i0], 1);
      atomicAdd(&lh[8 + i1], 1);
      tok_e01[t] = i0 | (i1 << 16);
      tok_w[t] = make_float2(w0, w1s);
      float4* lg = reinterpret_cast<float4*>(logits + (size_t)t * NEXP);
      lg[0] = make_float4(acc[0], acc[1], acc[2], acc[3]);
      lg[1] = make_float4(acc[4], acc[5], acc[6], acc[7]);
    }
  }
  __syncthreads();
  if (tid < 16) bh[blockIdx.x * 16 + tid] = lh[tid];

  // ---- fused weight cast tail (grid-stride; no sync needed) ----
  const int gstride = gridDim.x * blockDim.x;          // 262144 threads
  const int gidx = blockIdx.x * blockDim.x + tid;
  const int q4 = (NEXP * INTERM * HID) >> 2;           // 4.19M float4 per tensor
  for (int i = gidx; i < q4; i += gstride) {
    float4 v = reinterpret_cast<const float4*>(w1)[i];
    ushort4 o;
    o.x = f2bf(v.x); o.y = f2bf(v.y); o.z = f2bf(v.z); o.w = f2bf(v.w);
    reinterpret_cast<ushort4*>(w1b)[i] = o;
  }
  for (int i = gidx; i < q4; i += gstride) {
    float4 v = reinterpret_cast<const float4*>(w2)[i];
    ushort4 o;
    o.x = f2bf(v.x); o.y = f2bf(v.y); o.z = f2bf(v.z); o.w = f2bf(v.w);
    reinterpret_cast<ushort4*>(w2b)[i] = o;
  }
}

// ---------- parallel schedule: column prefix scans + 128-row tile emission ----------
// Single tile list (expert-grouped rows) used by BOTH GEMMs.
__global__ __launch_bounds__(1024) void sched_kernel(
    const int* __restrict__ bh, int* __restrict__ bhp, int* __restrict__ colbase,
    int4* __restrict__ sched1, int* __restrict__ nsched) {
  const int tid = threadIdx.x;
  const int w = tid >> 6;
  const int lane = tid & 63;
  __shared__ int ct[16];
  __shared__ int offs[8];
  __shared__ int t1o[8];

  int carry = 0;
  for (int ch = 0; ch < 16; ++ch) {
    int b = ch * 64 + lane;
    int v = bh[b * 16 + w];
    int incl = v;
#pragma unroll
    for (int d = 1; d < 64; d <<= 1) {
      int tt = __shfl_up(incl, d, 64);
      if (lane >= d) incl += tt;
    }
    bhp[b * 16 + w] = incl - v + carry;
    carry += __shfl(incl, 63, 64);
  }
  if (lane == 0) ct[w] = carry;
  __syncthreads();
  if (tid == 0) {
    int o = 0, s1 = 0;
    for (int e = 0; e < NEXP; ++e) {
      offs[e] = o;
      int n = ct[e] + ct[8 + e];
      o += n;
      t1o[e] = s1;
      s1 += (n + 127) >> 7;
    }
    nsched[0] = s1;
  }
  __syncthreads();
  if (tid < 16) colbase[tid] = offs[tid & 7] + ((tid & 8) ? ct[tid & 7] : 0);
  if (tid < 8) {
    int e = tid;
    int n = ct[e] + ct[8 + e], o = offs[e];
    for (int i = 0, t0 = 0; t0 < n; t0 += 128, ++i) {
      int hi = t0 + 128 < n ? t0 + 128 : n;
      sched1[t1o[e] + i] = make_int4(o + t0, o + hi, e, 0);
    }
  }
}

// ---------- scatter: per-block LDS ranks + precomputed bases ----------
__global__ __launch_bounds__(64) void scatter_kernel(
    const int* __restrict__ tok_e01, const float2* __restrict__ tok_w,
    const int* __restrict__ bhp, const int* __restrict__ colbase,
    int* __restrict__ row_token, float* __restrict__ row_weight,
    int2* __restrict__ tok_pos) {
  __shared__ int lh[16];
  const int tid = threadIdx.x;
  if (tid < 16) lh[tid] = 0;
  __syncthreads();
  if (tid < 16) {
    int t = blockIdx.x * 16 + tid;
    int p = tok_e01[t];
    int e0 = p & 0xffff, e1 = p >> 16;
    float2 w = tok_w[t];
    int r0 = atomicAdd(&lh[e0], 1);
    int pos0 = colbase[e0] + bhp[blockIdx.x * 16 + e0] + r0;
    row_token[pos0] = t; row_weight[pos0] = w.x;
    int r1 = atomicAdd(&lh[8 + e1], 1);
    int pos1 = colbase[8 + e1] + bhp[blockIdx.x * 16 + 8 + e1] + r1;
    row_token[pos1] = t; row_weight[pos1] = w.y;
    tok_pos[t] = make_int2(pos0, pos1);
  }
}

// ---------- grouped GEMM 128x128xBK64, 4 waves, m97-structure ----------
// R9-proven occupancy config: __launch_bounds__(256,4) -> VGPR 64, ~5 blk/CU.
// T2 both-sides swizzle (bank conflicts 0, verified R5-R15).
// Epilogue n-innermost + hoisted bias (R13: fixed 2x write amplification).
// XCD map: 2 XCDs per sid (R15; FETCH 244 MB as modeled). GEMMs sit at the
// m97-structure issue ceiling (MfmaUtil 35% vs m98's 37%); R15 proved fill
// reduction no longer moves time -> structure is the bound, map frozen.
//   xcd = 2*(sid&3) + col/HC;  j = (sid>>2)*HC + col%HC  (HC=NCOL/2, bijective)
// MODE 0: A gathered via row_token, epilogue gelu(.+b1) -> h (bf16)
// MODE 1: A = h rows (contiguous), epilogue y[row] = bf16(w*(acc+b2))
template <int MODE, int KDIM, int NDIM>
__global__ __launch_bounds__(256, 4) void gemm128_kernel(
    const unsigned short* __restrict__ A, const unsigned short* __restrict__ Bw,
    const float* __restrict__ bias, unsigned short* __restrict__ hOut,
    const int* __restrict__ row_token, const float* __restrict__ row_weight,
    const int4* __restrict__ sched, const int* __restrict__ nsched_p) {
  constexpr int NCOL = NDIM / 128;
  constexpr int HC = NCOL / 2;            // col-blocks per XCD per sid
  const int xcd = blockIdx.x & 7;         // round-robin XCD assignment
  const int j = blockIdx.x >> 3;          // per-XCD block index
  const int sid = 4 * (j / HC) + (xcd >> 1);
  const int colblk = (xcd & 1) * HC + (j % HC);
  if (sid >= nsched_p[0]) return;
  int4 s = sched[sid];
  const int row_start = s.x, row_limit = s.y, e = s.z;
  const int colBase = colblk * 128;

  __shared__ __attribute__((aligned(16))) unsigned short As[128 * 64];  // 16 KB
  __shared__ __attribute__((aligned(16))) unsigned short Bs[128 * 64];  // 16 KB

  const int tid = threadIdx.x;
  const int wave = tid >> 6;
  const int lane = tid & 63;
  const int wr = wave >> 1;  // 0..1 (M half)
  const int wc = wave & 1;   // 0..1 (N half)

  // staging: thread covers (row = i*32 + tid>>3, phys chunk tid&7); T2 write
  // side fetches logical chunk (tid&7)^(row&7), row&7 == (tid>>3)&7
  const int schunk = (tid & 7) ^ ((tid >> 3) & 7);
  const unsigned short* aG[4];
  const unsigned short* bG[4];
  const unsigned short* Bbase = Bw + (size_t)e * ((size_t)NDIM * KDIM);
#pragma unroll
  for (int i = 0; i < 4; ++i) {
    int r = i * 32 + (tid >> 3);
    int rg = row_start + r;
    rg = rg < row_limit ? rg : (row_limit - 1);  // clamp partial tiles
    int arow = (MODE == 0) ? row_token[rg] : rg;
    aG[i] = A + (size_t)arow * KDIM + schunk * 8;
    bG[i] = Bbase + (size_t)(colBase + r) * KDIM + schunk * 8;
  }

  f32x4 zero = {0.f, 0.f, 0.f, 0.f};
  f32x4 acc[4][4];
#pragma unroll
  for (int m = 0; m < 4; ++m)
#pragma unroll
    for (int n = 0; n < 4; ++n) acc[m][n] = zero;

  const int rl = lane & 15;
  const int ch0 = lane >> 4;
  const int swz = rl & 7;
  const int cOff0 = (ch0 ^ swz) * 16;        // ks0 swizzled chunk byte
  const int cOff1 = ((4 + ch0) ^ swz) * 16;  // ks1
  const int arB = (wr * 64 + rl) * 128;      // A frag row-base byte (+m*2048)
  const int brB = (wc * 64 + rl) * 128;      // B frag row-base byte (+n*2048)

  for (int kt = 0; kt < KDIM / 64; ++kt) {
    if (kt) __syncthreads();  // all waves done reading previous tile
    const size_t koff = (size_t)kt * 64;  // elements (128 B)
#pragma unroll
    for (int i = 0; i < 4; ++i) {
      async16(aG[i] + koff, (char*)As + (i * 4 + wave) * 1024);
      async16(bG[i] + koff, (char*)Bs + (i * 4 + wave) * 1024);
    }
    __syncthreads();  // compiler drains vmcnt(0) before s_barrier: tile ready
#pragma unroll
    for (int ks = 0; ks < 2; ++ks) {
      const int co = ks ? cOff1 : cOff0;
      bf16x8 af[4], bfr[4];
#pragma unroll
      for (int m = 0; m < 4; ++m)
        af[m] = *reinterpret_cast<const bf16x8*>((const char*)As + arB + m * 2048 + co);
#pragma unroll
      for (int n = 0; n < 4; ++n)
        bfr[n] = *reinterpret_cast<const bf16x8*>((const char*)Bs + brB + n * 2048 + co);
#pragma unroll
      for (int m = 0; m < 4; ++m)
#pragma unroll
        for (int n = 0; n < 4; ++n)
          acc[m][n] = __builtin_amdgcn_mfma_f32_16x16x32_bf16(af[m], bfr[n], acc[m][n], 0, 0, 0);
    }
  }

  // epilogue: C/D map col=lane&15, row=(lane>>4)*4+j
  const int cCol = lane & 15;
  const int cRowB = (lane >> 4) * 4;

  // hoist per-lane bias values (4 cols, stride 16)
  float bb[4];
#pragma unroll
  for (int n = 0; n < 4; ++n)
    bb[n] = bias[e * NDIM + colBase + wc * 64 + n * 16 + cCol];

  if (MODE == 0) {
#pragma unroll
    for (int m = 0; m < 4; ++m) {
#pragma unroll
      for (int jj = 0; jj < 4; ++jj) {
        int r = row_start + wr * 64 + m * 16 + cRowB + jj;
        if (r < row_limit) {
          unsigned short* hrow = hOut + (size_t)r * NDIM + colBase + wc * 64 + cCol;
#pragma unroll
          for (int n = 0; n < 4; ++n)
            hrow[n * 16] = f2bf(gelu_fast(acc[m][n][jj] + bb[n]));
        }
      }
    }
  } else {
#pragma unroll
    for (int m = 0; m < 4; ++m) {
#pragma unroll
      for (int jj = 0; jj < 4; ++jj) {
        int rr = row_start + wr * 64 + m * 16 + cRowB + jj;
        if (rr < row_limit) {
          float wgt = row_weight[rr];
          unsigned short* yrow = hOut + (size_t)rr * NDIM + colBase + wc * 64 + cCol;
#pragma unroll
          for (int n = 0; n < 4; ++n)
            yrow[n * 16] = f2bf(wgt * (acc[m][n][jj] + bb[n]));
        }
      }
    }
  }
}

// ---------- combine: out[t] = y[pos0] + y[pos1] (wave per token, 16B ops) ----------
typedef unsigned short ushort8 __attribute__((ext_vector_type(8)));

__global__ __launch_bounds__(256) void combine_kernel(
    const unsigned short* __restrict__ y, const int2* __restrict__ tok_pos,
    float* __restrict__ out) {
  const int t = blockIdx.x * 4 + (threadIdx.x >> 6);
  const int lane = threadIdx.x & 63;
  int2 p = tok_pos[t];
  const ushort8* y0 = reinterpret_cast<const ushort8*>(y + (size_t)p.x * HID);
  const ushort8* y1 = reinterpret_cast<const ushort8*>(y + (size_t)p.y * HID);
  float4* o = reinterpret_cast<float4*>(out + (size_t)t * HID);
#pragma unroll
  for (int q = 0; q < 2; ++q) {
    ushort8 a = y0[q * 64 + lane];
    ushort8 b = y1[q * 64 + lane];
    float4 r0, r1;
    r0.x = bf2f(a[0]) + bf2f(b[0]);
    r0.y = bf2f(a[1]) + bf2f(b[1]);
    r0.z = bf2f(a[2]) + bf2f(b[2]);
    r0.w = bf2f(a[3]) + bf2f(b[3]);
    r1.x = bf2f(a[4]) + bf2f(b[4]);
    r1.y = bf2f(a[5]) + bf2f(b[5]);
    r1.z = bf2f(a[6]) + bf2f(b[6]);
    r1.w = bf2f(a[7]) + bf2f(b[7]);
    o[(q * 64 + lane) * 2] = r0;
    o[(q * 64 + lane) * 2 + 1] = r1;
  }
}

// ---------- launch ----------
extern "C" void kernel_launch(void* const* d_in, const int* in_sizes, int n_in,
                              void* d_out, int out_size, void* d_ws, size_t ws_size,
                              hipStream_t stream) {
  const float* x  = (const float*)d_in[0];
  const float* gw = (const float*)d_in[1];
  const float* w1 = (const float*)d_in[2];
  const float* b1 = (const float*)d_in[3];
  const float* w2 = (const float*)d_in[4];
  const float* b2 = (const float*)d_in[5];
  float* out = (float*)d_out;
  float* logits = out + (size_t)T_TOKENS * HID;

  char* ws = (char*)d_ws;
  int* nsched = (int*)ws;
  int* colbase = (int*)(ws + 64);
  int4* sched1  = (int4*)(ws + 512);               // <=264 entries
  int* tok_e01 = (int*)(ws + 16384);                              // 64 KB
  float2* tok_w = (float2*)(ws + 16384 + 65536);                  // 128 KB
  int* row_token = (int*)(ws + 16384 + 65536 + 131072);           // 128 KB
  float* row_weight = (float*)(ws + 16384 + 65536 + 2 * 131072);  // 128 KB
  int* bh  = (int*)(ws + 16384 + 65536 + 3 * 131072);             // 64 KB
  int* bhp = bh + 16384;                                          // 64 KB
  int2* tok_pos = (int2*)(ws + 16384 + 65536 + 3 * 131072 + 2 * 65536);  // 128 KB
  const size_t BIG = 1u << 20;
  unsigned short* xb  = (unsigned short*)(ws + BIG);  // 32 MiB
  unsigned short* w1b = xb  + (size_t)16777216;       // 32 MiB
  unsigned short* w2b = w1b + (size_t)16777216;       // 32 MiB
  unsigned short* h   = w2b + (size_t)16777216;       // 128 MiB
  // y (32768 x 1024 bf16 = 64 MiB) aliases [xb, w1b]: both dead after GEMM1
  unsigned short* y = xb;
  const size_t REQUIRED = BIG + 3ull * 33554432ull + 134217728ull;
  if (ws_size < REQUIRED) return;

  // routing + x-cast + WEIGHT casts, one dispatch (cast tail is grid-stride)
  routing_kernel<<<1024, 256, 0, stream>>>(x, gw, logits, xb, bh, tok_e01, tok_w,
                                           w1, w1b, w2, w2b);
  sched_kernel<<<1, 1024, 0, stream>>>(bh, bhp, colbase, sched1, nsched);
  scatter_kernel<<<1024, 64, 0, stream>>>(tok_e01, tok_w, bhp, colbase,
                                          row_token, row_weight, tok_pos);
  // GEMM1: h = gelu(x @ w1^T + b1); flat 4224 = 8 xcd x 66 groups x HC(8)
  gemm128_kernel<0, 1024, 2048><<<4224, 256, 0, stream>>>(
      xb, w1b, b1, h, row_token, nullptr, sched1, nsched);
  // GEMM2 single pass: y[row] = bf16(w*(h @ w2^T + b2)); 2112 = 8 x 66 x HC(4)
  gemm128_kernel<1, 2048, 1024><<<2112, 256, 0, stream>>>(
      h, w2b, b2, y, row_token, row_weight, sched1, nsched);
  // combine: out[t] = y[pos0(t)] + y[pos1(t)]
  combine_kernel<<<4096, 256, 0, stream>>>(y, tok_pos, out);
}